// Round 1
// baseline (5060.811 us; speedup 1.0000x reference)
//
#include <hip/hip_runtime.h>
#include <math.h>

#define NBATCH 16
#define NSEQ   512
#define NDIM   1024
#define NEGBIG (-1e30f)

// XOR-swizzled LDS addressing: tiles are [rows][32 floats] stored as 8
// float4-chunks per row; chunk index XORed with (row>>3) so that strided
// row reads (ds_read_b128) land in different bank groups (<=2-way).
__device__ __forceinline__ int swz(int row, int chunk){
  return (row << 5) + (((chunk ^ (row >> 3)) & 7) << 2);
}

// ---------------- mask compaction ----------------
__global__ __launch_bounds__(512)
void k_compact(const int* __restrict__ am, const int* __restrict__ tt,
               int* __restrict__ idx0, int* __restrict__ idx1,
               int* __restrict__ n0, int* __restrict__ n1){
  int b = blockIdx.x, t = threadIdx.x;
  int a = am[b * NSEQ + t];
  int y = tt[b * NSEQ + t];
  bool p0 = (a == 1) && (y == 0);
  bool p1 = (a == 1) && (y == 1);
  __shared__ int wc0[8], wc1[8], wo0[8], wo1[8];
  int wave = t >> 6, lane = t & 63;
  unsigned long long m0 = __ballot(p0);
  unsigned long long m1 = __ballot(p1);
  unsigned long long below = (1ULL << lane) - 1ULL;
  int r0 = __popcll(m0 & below);
  int r1 = __popcll(m1 & below);
  if (lane == 0){ wc0[wave] = __popcll(m0); wc1[wave] = __popcll(m1); }
  __syncthreads();
  if (t == 0){
    int s0 = 0, s1 = 0;
    for (int w = 0; w < 8; ++w){ wo0[w] = s0; s0 += wc0[w]; wo1[w] = s1; s1 += wc1[w]; }
    n0[b] = s0; n1[b] = s1;
  }
  __syncthreads();
  if (p0) idx0[b * NSEQ + wo0[wave] + r0] = t;
  if (p1) idx1[b * NSEQ + wo1[wave] + r1] = t;
}

// ---------------- per-row 1/max(||x||,eps) ----------------
__global__ __launch_bounds__(256)
void k_rnorm(const float* __restrict__ emb, float* __restrict__ rnorm){
  int wave = threadIdx.x >> 6, lane = threadIdx.x & 63;
  int row = blockIdx.x * 4 + wave;
  const float4* p = (const float4*)(emb + (size_t)row * NDIM);
  float ss = 0.f;
  #pragma unroll
  for (int i = 0; i < 4; ++i){
    float4 v = p[i * 64 + lane];
    ss += v.x*v.x + v.y*v.y + v.z*v.z + v.w*v.w;
  }
  #pragma unroll
  for (int off = 32; off > 0; off >>= 1) ss += __shfl_down(ss, off, 64);
  if (lane == 0) rnorm[row] = 1.f / fmaxf(sqrtf(ss), 1e-12f);
}

// ---------------- compacted Q/K projection GEMM ----------------
// blockIdx.x: row-tile (64 rows of the compact list), blockIdx.y: col-tile
// (128 of 1024 outputs), blockIdx.z = b*2 + which (0=Q,1=K).
// 128 threads, 8x8 outputs/thread, BK=32.
__global__ __launch_bounds__(128)
void k_proj(const float* __restrict__ emb, const float* __restrict__ Wq,
            const float* __restrict__ bq, const float* __restrict__ Wk,
            const float* __restrict__ bk, const int* __restrict__ idx0,
            const int* __restrict__ idx1, const int* __restrict__ n0,
            const int* __restrict__ n1, float* __restrict__ P){
  int z = blockIdx.z;
  int b = z >> 1, which = z & 1;
  int cnt = which ? n1[b] : n0[b];
  int rbase = blockIdx.x << 6;
  if (rbase >= cnt) return;
  const float* __restrict__ W    = which ? Wk : Wq;
  const float* __restrict__ bias = which ? bk : bq;
  const int*   __restrict__ idx  = (which ? idx1 : idx0) + b * NSEQ;
  int dstOff = which ? n0[b] : 0;
  int cbase = blockIdx.y << 7;

  __shared__ __align__(16) float As[64 * 32];
  __shared__ __align__(16) float Bs[128 * 32];

  int t = threadIdx.x;
  int tx = t & 15, ty = t >> 4;     // col group 0..15 (8 cols), row group 0..7 (8 rows)
  int lrow = t >> 3;                // 0..15: loader base row
  int lchunk = t & 7;               // float4 chunk in row

  const float* aptr[4];
  #pragma unroll
  for (int u = 0; u < 4; ++u){
    int r = rbase + lrow + (u << 4);
    int cr = min(r, cnt - 1);
    aptr[u] = emb + ((size_t)b * NSEQ + idx[cr]) * NDIM;
  }
  const float* bptr[8];
  #pragma unroll
  for (int u = 0; u < 8; ++u){
    bptr[u] = W + (size_t)(cbase + lrow + (u << 4)) * NDIM;
  }

  float acc[8][8];
  #pragma unroll
  for (int i = 0; i < 8; ++i)
    #pragma unroll
    for (int j = 0; j < 8; ++j) acc[i][j] = 0.f;

  for (int k0 = 0; k0 < NDIM; k0 += 32){
    float4 av[4], bv[8];
    #pragma unroll
    for (int u = 0; u < 4; ++u) av[u] = *(const float4*)(aptr[u] + k0 + (lchunk << 2));
    #pragma unroll
    for (int u = 0; u < 8; ++u) bv[u] = *(const float4*)(bptr[u] + k0 + (lchunk << 2));
    __syncthreads();
    #pragma unroll
    for (int u = 0; u < 4; ++u) *(float4*)&As[swz(lrow + (u << 4), lchunk)] = av[u];
    #pragma unroll
    for (int u = 0; u < 8; ++u) *(float4*)&Bs[swz(lrow + (u << 4), lchunk)] = bv[u];
    __syncthreads();
    #pragma unroll
    for (int k4 = 0; k4 < 8; ++k4){
      float4 a4[8], b4[8];
      #pragma unroll
      for (int i = 0; i < 8; ++i) a4[i] = *(const float4*)&As[swz(ty * 8 + i, k4)];
      #pragma unroll
      for (int j = 0; j < 8; ++j) b4[j] = *(const float4*)&Bs[swz(tx * 8 + j, k4)];
      #pragma unroll
      for (int i = 0; i < 8; ++i)
        #pragma unroll
        for (int j = 0; j < 8; ++j)
          acc[i][j] += a4[i].x*b4[j].x + a4[i].y*b4[j].y + a4[i].z*b4[j].z + a4[i].w*b4[j].w;
    }
  }

  #pragma unroll
  for (int i = 0; i < 8; ++i){
    int r = rbase + ty * 8 + i;
    if (r < cnt){
      float* dst = P + ((size_t)b * NSEQ + dstOff + r) * NDIM + cbase + (tx << 3);
      float4 o0, o1;
      o0.x = acc[i][0] + bias[cbase + (tx << 3) + 0];
      o0.y = acc[i][1] + bias[cbase + (tx << 3) + 1];
      o0.z = acc[i][2] + bias[cbase + (tx << 3) + 2];
      o0.w = acc[i][3] + bias[cbase + (tx << 3) + 3];
      o1.x = acc[i][4] + bias[cbase + (tx << 3) + 4];
      o1.y = acc[i][5] + bias[cbase + (tx << 3) + 5];
      o1.z = acc[i][6] + bias[cbase + (tx << 3) + 6];
      o1.w = acc[i][7] + bias[cbase + (tx << 3) + 7];
      *(float4*)dst = o0;
      *(float4*)(dst + 4) = o1;
    }
  }
}

// ---------------- pair phase: logits + |cos| + flash-style tile partials ----
// 32x32 pair tile per 1-wave block; two K=1024 dot-GEMMs (q.k and e.e),
// then online (max, sum exp, sum exp*score) reduced across the wave.
__global__ __launch_bounds__(64)
void k_pair(const float* __restrict__ emb, const float* __restrict__ P,
            const int* __restrict__ idx0, const int* __restrict__ idx1,
            const int* __restrict__ n0a, const int* __restrict__ n1a,
            const float* __restrict__ rnorm, float* __restrict__ partials){
  int b = blockIdx.z;
  int nn0 = n0a[b], nn1 = n1a[b];
  int ibase = blockIdx.x << 5, jbase = blockIdx.y << 5;
  if (ibase >= nn0 || jbase >= nn1) return;

  __shared__ __align__(16) float Qs[32*32], Ks[32*32], Es[32*32], Fs[32*32];
  int lane = threadIdx.x;
  int tx = lane & 7, ty = lane >> 3;
  int lrow = lane >> 3, lchunk = lane & 7;

  const float* qptr[4]; const float* kptr[4];
  const float* eptr[4]; const float* fptr[4];
  #pragma unroll
  for (int u = 0; u < 4; ++u){
    int ri = ibase + lrow + (u << 3); int ci = min(ri, nn0 - 1);
    int rj = jbase + lrow + (u << 3); int cj = min(rj, nn1 - 1);
    qptr[u] = P + ((size_t)b * NSEQ + ci) * NDIM;
    kptr[u] = P + ((size_t)b * NSEQ + nn0 + cj) * NDIM;
    eptr[u] = emb + ((size_t)b * NSEQ + idx0[b * NSEQ + ci]) * NDIM;
    fptr[u] = emb + ((size_t)b * NSEQ + idx1[b * NSEQ + cj]) * NDIM;
  }

  float accL[4][4], accS[4][4];
  #pragma unroll
  for (int i = 0; i < 4; ++i)
    #pragma unroll
    for (int j = 0; j < 4; ++j){ accL[i][j] = 0.f; accS[i][j] = 0.f; }

  for (int k0 = 0; k0 < NDIM; k0 += 32){
    float4 qv[4], kv[4];
    #pragma unroll
    for (int u = 0; u < 4; ++u){
      qv[u] = *(const float4*)(qptr[u] + k0 + (lchunk << 2));
      kv[u] = *(const float4*)(kptr[u] + k0 + (lchunk << 2));
    }
    __syncthreads();
    #pragma unroll
    for (int u = 0; u < 4; ++u){
      *(float4*)&Qs[swz(lrow + (u << 3), lchunk)] = qv[u];
      *(float4*)&Ks[swz(lrow + (u << 3), lchunk)] = kv[u];
    }
    float4 ev[4], fv[4];
    #pragma unroll
    for (int u = 0; u < 4; ++u){
      ev[u] = *(const float4*)(eptr[u] + k0 + (lchunk << 2));
      fv[u] = *(const float4*)(fptr[u] + k0 + (lchunk << 2));
    }
    #pragma unroll
    for (int u = 0; u < 4; ++u){
      *(float4*)&Es[swz(lrow + (u << 3), lchunk)] = ev[u];
      *(float4*)&Fs[swz(lrow + (u << 3), lchunk)] = fv[u];
    }
    __syncthreads();
    #pragma unroll
    for (int k4 = 0; k4 < 8; ++k4){
      float4 q4[4], k4v[4], e4[4], f4[4];
      #pragma unroll
      for (int i = 0; i < 4; ++i){
        q4[i] = *(const float4*)&Qs[swz(ty * 4 + i, k4)];
        e4[i] = *(const float4*)&Es[swz(ty * 4 + i, k4)];
      }
      #pragma unroll
      for (int j = 0; j < 4; ++j){
        k4v[j] = *(const float4*)&Ks[swz(tx * 4 + j, k4)];
        f4[j]  = *(const float4*)&Fs[swz(tx * 4 + j, k4)];
      }
      #pragma unroll
      for (int i = 0; i < 4; ++i)
        #pragma unroll
        for (int j = 0; j < 4; ++j){
          accL[i][j] += q4[i].x*k4v[j].x + q4[i].y*k4v[j].y + q4[i].z*k4v[j].z + q4[i].w*k4v[j].w;
          accS[i][j] += e4[i].x*f4[j].x  + e4[i].y*f4[j].y  + e4[i].z*f4[j].z  + e4[i].w*f4[j].w;
        }
    }
  }

  // validity + row norms for score scaling
  int vi[4], vj[4]; float rnI[4], rnJ[4];
  #pragma unroll
  for (int i = 0; i < 4; ++i){
    int g = ibase + ty * 4 + i; vi[i] = (g < nn0);
    int cg = min(g, nn0 - 1);
    rnI[i] = rnorm[b * NSEQ + idx0[b * NSEQ + cg]];
  }
  #pragma unroll
  for (int j = 0; j < 4; ++j){
    int g = jbase + tx * 4 + j; vj[j] = (g < nn1);
    int cg = min(g, nn1 - 1);
    rnJ[j] = rnorm[b * NSEQ + idx1[b * NSEQ + cg]];
  }

  float m = NEGBIG, dsum = 0.f, nsum = 0.f;
  #pragma unroll
  for (int i = 0; i < 4; ++i)
    #pragma unroll
    for (int j = 0; j < 4; ++j)
      if (vi[i] && vj[j]) m = fmaxf(m, accL[i][j]);
  #pragma unroll
  for (int i = 0; i < 4; ++i)
    #pragma unroll
    for (int j = 0; j < 4; ++j)
      if (vi[i] && vj[j]){
        float e = expf(accL[i][j] - m);
        dsum += e;
        nsum += e * fabsf(accS[i][j]) * rnI[i] * rnJ[j];
      }

  #pragma unroll
  for (int off = 1; off < 64; off <<= 1){
    float m2 = __shfl_xor(m, off, 64);
    float d2 = __shfl_xor(dsum, off, 64);
    float s2 = __shfl_xor(nsum, off, 64);
    float mm = fmaxf(m, m2);
    float w1 = expf(m - mm), w2 = expf(m2 - mm);
    dsum = dsum * w1 + d2 * w2;
    nsum = nsum * w1 + s2 * w2;
    m = mm;
  }
  if (lane == 0){
    float* pp = partials + ((size_t)b * 256 + (blockIdx.x << 4) + blockIdx.y) * 3;
    pp[0] = m; pp[1] = dsum; pp[2] = nsum;
  }
}

// ---------------- finalize: merge tile partials per batch ----------------
__global__ __launch_bounds__(64)
void k_final(const float* __restrict__ partials, const int* __restrict__ n0a,
             const int* __restrict__ n1a, float* __restrict__ out){
  int b = blockIdx.x, lane = threadIdx.x;
  int nn0 = n0a[b], nn1 = n1a[b];
  float m = NEGBIG, d = 0.f, n = 0.f;
  if (nn0 > 0 && nn1 > 0){
    int nti = (nn0 + 31) >> 5, ntj = (nn1 + 31) >> 5;
    int cnt = nti * ntj;
    for (int s = lane; s < cnt; s += 64){
      int it = s / ntj, jt = s - it * ntj;
      const float* pp = partials + ((size_t)b * 256 + (it << 4) + jt) * 3;
      float m2 = pp[0], d2 = pp[1], n2 = pp[2];
      float mm = fmaxf(m, m2);
      float w1 = expf(m - mm), w2 = expf(m2 - mm);
      d = d * w1 + d2 * w2;
      n = n * w1 + n2 * w2;
      m = mm;
    }
  }
  #pragma unroll
  for (int off = 1; off < 64; off <<= 1){
    float m2 = __shfl_xor(m, off, 64);
    float d2 = __shfl_xor(d, off, 64);
    float n2 = __shfl_xor(n, off, 64);
    float mm = fmaxf(m, m2);
    float w1 = expf(m - mm), w2 = expf(m2 - mm);
    d = d * w1 + d2 * w2;
    n = n * w1 + n2 * w2;
    m = mm;
  }
  if (lane == 0) out[b] = (d > 0.f) ? (n / d) : 0.f;
}

extern "C" void kernel_launch(void* const* d_in, const int* in_sizes, int n_in,
                              void* d_out, int out_size, void* d_ws, size_t ws_size,
                              hipStream_t stream) {
  const float* emb = (const float*)d_in[0];
  const float* Wq  = (const float*)d_in[1];
  const float* bq  = (const float*)d_in[2];
  const float* Wk  = (const float*)d_in[3];
  const float* bk  = (const float*)d_in[4];
  const int*   am  = (const int*)d_in[5];
  const int*   tt  = (const int*)d_in[6];
  float* out = (float*)d_out;

  char* ws = (char*)d_ws;
  float* P     = (float*)ws;                           // 16*512*1024 f32 = 32 MiB
  int*   idx0  = (int*)(ws + 33554432);                // 16*512 i32
  int*   idx1  = idx0 + NBATCH * NSEQ;
  int*   n0    = idx1 + NBATCH * NSEQ;
  int*   n1    = n0 + NBATCH;
  float* rnorm = (float*)(n1 + NBATCH);                // 16*512 f32
  float* partials = rnorm + NBATCH * NSEQ;             // 16*256*3 f32

  k_compact<<<dim3(NBATCH), dim3(NSEQ), 0, stream>>>(am, tt, idx0, idx1, n0, n1);
  k_rnorm<<<dim3(NBATCH * NSEQ / 4), dim3(256), 0, stream>>>(emb, rnorm);
  k_proj<<<dim3(8, 8, NBATCH * 2), dim3(128), 0, stream>>>(emb, Wq, bq, Wk, bk,
                                                           idx0, idx1, n0, n1, P);
  k_pair<<<dim3(16, 16, NBATCH), dim3(64), 0, stream>>>(emb, P, idx0, idx1,
                                                        n0, n1, rnorm, partials);
  k_final<<<dim3(NBATCH), dim3(64), 0, stream>>>(partials, n0, n1, out);
}

// Round 7
// 1935.947 us; speedup vs baseline: 2.6141x; 2.6141x over previous
//
#include <hip/hip_runtime.h>
#include <math.h>

#define NBATCH 16
#define NSEQ   512
#define NDIM   1024
#define NEGBIG (-1e30f)

typedef __attribute__((ext_vector_type(8))) short bf16x8;
typedef __attribute__((ext_vector_type(4))) float f32x4;

// XOR-swizzled LDS addressing for [rows][32-float] tiles stored as 8
// float4-chunks per row; chunk index XORed with (row>>3) so strided row
// reads (ds_read_b128) spread across bank groups (<=2-way aliasing = free).
__device__ __forceinline__ int swz(int row, int chunk){
  return (row << 5) + (((chunk ^ (row >> 3)) & 7) << 2);
}

// split f32 -> bf16 hi + bf16 lo (truncation split: hi = top16 bits,
// lo = bf16(f - hi)); a*b ~= ahi*bhi + ahi*blo + alo*bhi (drop lo*lo).
__device__ __forceinline__ void split_bf16(const float* s, bf16x8& hi, bf16x8& lo){
  #pragma unroll
  for (int i = 0; i < 8; ++i){
    float f = s[i];
    unsigned u  = __float_as_uint(f);
    unsigned hb = u & 0xffff0000u;
    float fl = f - __uint_as_float(hb);
    hi[i] = (short)(hb >> 16);
    lo[i] = (short)(__float_as_uint(fl) >> 16);
  }
}

// ---------------- mask compaction ----------------
__global__ __launch_bounds__(512)
void k_compact(const int* __restrict__ am, const int* __restrict__ tt,
               int* __restrict__ idx0, int* __restrict__ idx1,
               int* __restrict__ n0, int* __restrict__ n1){
  int b = blockIdx.x, t = threadIdx.x;
  int a = am[b * NSEQ + t];
  int y = tt[b * NSEQ + t];
  bool p0 = (a == 1) && (y == 0);
  bool p1 = (a == 1) && (y == 1);
  __shared__ int wc0[8], wc1[8], wo0[8], wo1[8];
  int wave = t >> 6, lane = t & 63;
  unsigned long long m0 = __ballot(p0);
  unsigned long long m1 = __ballot(p1);
  unsigned long long below = (1ULL << lane) - 1ULL;
  int r0 = __popcll(m0 & below);
  int r1 = __popcll(m1 & below);
  if (lane == 0){ wc0[wave] = __popcll(m0); wc1[wave] = __popcll(m1); }
  __syncthreads();
  if (t == 0){
    int s0 = 0, s1 = 0;
    for (int w = 0; w < 8; ++w){ wo0[w] = s0; s0 += wc0[w]; wo1[w] = s1; s1 += wc1[w]; }
    n0[b] = s0; n1[b] = s1;
  }
  __syncthreads();
  if (p0) idx0[b * NSEQ + wo0[wave] + r0] = t;
  if (p1) idx1[b * NSEQ + wo1[wave] + r1] = t;
}

// ---------------- per-row 1/max(||x||,eps) ----------------
__global__ __launch_bounds__(256)
void k_rnorm(const float* __restrict__ emb, float* __restrict__ rnorm){
  int wave = threadIdx.x >> 6, lane = threadIdx.x & 63;
  int row = blockIdx.x * 4 + wave;
  const float4* p = (const float4*)(emb + (size_t)row * NDIM);
  float ss = 0.f;
  #pragma unroll
  for (int i = 0; i < 4; ++i){
    float4 v = p[i * 64 + lane];
    ss += v.x*v.x + v.y*v.y + v.z*v.z + v.w*v.w;
  }
  #pragma unroll
  for (int off = 32; off > 0; off >>= 1) ss += __shfl_down(ss, off, 64);
  if (lane == 0) rnorm[row] = 1.f / fmaxf(sqrtf(ss), 1e-12f);
}

// ---------------- SHADOW: bf16-split MFMA projection (perf probe only) ----
// Writes into P BEFORE the real k_proj, which then overwrites every row that
// k_pair reads (rows >= n0+n1 are never read downstream) -> numerics of this
// kernel cannot affect d_out. Purpose: measure MFMA-path timing + counters
// (MfmaUtil vs VALUBusy conversion split) in the same bench slot.
__global__ __launch_bounds__(256)
void k_proj_mfma(const float* __restrict__ emb, const float* __restrict__ Wq,
                 const float* __restrict__ bq, const float* __restrict__ Wk,
                 const float* __restrict__ bk, const int* __restrict__ idx0,
                 const int* __restrict__ idx1, const int* __restrict__ n0,
                 const int* __restrict__ n1, float* __restrict__ P){
  int z = blockIdx.z;
  int b = z >> 1, which = z & 1;
  int cnt = which ? n1[b] : n0[b];
  int rbase = blockIdx.x << 6;
  if (cnt == 0 || rbase >= cnt) return;
  const float* __restrict__ W    = which ? Wk : Wq;
  const float* __restrict__ bias = which ? bk : bq;
  const int*   __restrict__ idx  = (which ? idx1 : idx0) + b * NSEQ;
  int cbase = blockIdx.y << 7;

  __shared__ __align__(16) float As[64 * 32];
  __shared__ __align__(16) float Bs[128 * 32];

  int t = threadIdx.x;
  int w = t >> 6, lane = t & 63;
  int wm = w >> 1, wn = w & 1;       // wave tile: rows wm*32+0..31, cols wn*64+0..63
  int lrow = t >> 3, lchunk = t & 7; // staging loader (same as k_proj)
  int fr = lane & 15;                // fragment row (A) / col (B)
  int kg = lane >> 4;                // k-group 0..3 (8 contiguous k each)
  int c0 = kg << 1;                  // first float4-chunk of this lane's k

  const float* aptr[2];
  #pragma unroll
  for (int u = 0; u < 2; ++u){
    int r = rbase + lrow + (u << 5);
    int cr = min(r, cnt - 1);
    aptr[u] = emb + ((size_t)b * NSEQ + idx[cr]) * NDIM + (lchunk << 2);
  }
  const float* bptr[4];
  #pragma unroll
  for (int u = 0; u < 4; ++u)
    bptr[u] = W + (size_t)(cbase + lrow + (u << 5)) * NDIM + (lchunk << 2);

  f32x4 acc[2][4];
  #pragma unroll
  for (int i = 0; i < 2; ++i)
    #pragma unroll
    for (int j = 0; j < 4; ++j) acc[i][j] = (f32x4){0.f, 0.f, 0.f, 0.f};

  for (int k0 = 0; k0 < NDIM; k0 += 32){
    float4 av[2], bv[4];
    #pragma unroll
    for (int u = 0; u < 2; ++u) av[u] = *(const float4*)(aptr[u] + k0);
    #pragma unroll
    for (int u = 0; u < 4; ++u) bv[u] = *(const float4*)(bptr[u] + k0);
    __syncthreads();
    #pragma unroll
    for (int u = 0; u < 2; ++u) *(float4*)&As[swz(lrow + (u << 5), lchunk)] = av[u];
    #pragma unroll
    for (int u = 0; u < 4; ++u) *(float4*)&Bs[swz(lrow + (u << 5), lchunk)] = bv[u];
    __syncthreads();

    bf16x8 ahi[2], alo[2], bhi[4], blo[4];
    #pragma unroll
    for (int fm = 0; fm < 2; ++fm){
      int r = wm * 32 + fm * 16 + fr;
      float tmp[8];
      *(float4*)&tmp[0] = *(const float4*)&As[swz(r, c0)];
      *(float4*)&tmp[4] = *(const float4*)&As[swz(r, c0 + 1)];
      split_bf16(tmp, ahi[fm], alo[fm]);
    }
    #pragma unroll
    for (int fn = 0; fn < 4; ++fn){
      int r = wn * 64 + fn * 16 + fr;
      float tmp[8];
      *(float4*)&tmp[0] = *(const float4*)&Bs[swz(r, c0)];
      *(float4*)&tmp[4] = *(const float4*)&Bs[swz(r, c0 + 1)];
      split_bf16(tmp, bhi[fn], blo[fn]);
    }
    #pragma unroll
    for (int fm = 0; fm < 2; ++fm)
      #pragma unroll
      for (int fn = 0; fn < 4; ++fn){
        acc[fm][fn] = __builtin_amdgcn_mfma_f32_16x16x32_bf16(ahi[fm], bhi[fn], acc[fm][fn], 0, 0, 0);
        acc[fm][fn] = __builtin_amdgcn_mfma_f32_16x16x32_bf16(ahi[fm], blo[fn], acc[fm][fn], 0, 0, 0);
        acc[fm][fn] = __builtin_amdgcn_mfma_f32_16x16x32_bf16(alo[fm], bhi[fn], acc[fm][fn], 0, 0, 0);
      }
  }

  // C/D layout (m89-verified): col = lane&15, row = (lane>>4)*4 + reg
  #pragma unroll
  for (int fm = 0; fm < 2; ++fm)
    #pragma unroll
    for (int fn = 0; fn < 4; ++fn)
      #pragma unroll
      for (int reg = 0; reg < 4; ++reg){
        int gr = rbase + wm * 32 + fm * 16 + (kg << 2) + reg;   // < NSEQ always
        int gc = cbase + wn * 64 + fn * 16 + fr;
        P[((size_t)b * NSEQ + gr) * NDIM + gc] = acc[fm][fn][reg] + bias[gc];
      }
}

// ---------------- compacted Q/K projection GEMM (real path) ----------------
// 256 threads, BM=64 x BN=128 x BK=32, 4x8 per-thread tile (~110 VGPR, no spill).
__global__ __launch_bounds__(256)
void k_proj(const float* __restrict__ emb, const float* __restrict__ Wq,
            const float* __restrict__ bq, const float* __restrict__ Wk,
            const float* __restrict__ bk, const int* __restrict__ idx0,
            const int* __restrict__ idx1, const int* __restrict__ n0,
            const int* __restrict__ n1, float* __restrict__ P){
  int z = blockIdx.z;
  int b = z >> 1, which = z & 1;
  int cnt = which ? n1[b] : n0[b];
  int rbase = blockIdx.x << 6;
  if (cnt == 0 || rbase >= cnt) return;
  const float* __restrict__ W    = which ? Wk : Wq;
  const float* __restrict__ bias = which ? bk : bq;
  const int*   __restrict__ idx  = (which ? idx1 : idx0) + b * NSEQ;
  int dstOff = which ? n0[b] : 0;
  int cbase = blockIdx.y << 7;

  __shared__ __align__(16) float As[64 * 32];
  __shared__ __align__(16) float Bs[128 * 32];

  int t = threadIdx.x;
  int tx = t & 15, ty = t >> 4;     // tx: 8-col group (0..15), ty: 4-row group (0..15)
  int lrow = t >> 3, lchunk = t & 7; // loader: row 0..31, float4-chunk 0..7

  const float* aptr[2];
  #pragma unroll
  for (int u = 0; u < 2; ++u){
    int r = rbase + lrow + (u << 5);
    int cr = min(r, cnt - 1);
    aptr[u] = emb + ((size_t)b * NSEQ + idx[cr]) * NDIM + (lchunk << 2);
  }
  const float* bptr[4];
  #pragma unroll
  for (int u = 0; u < 4; ++u)
    bptr[u] = W + (size_t)(cbase + lrow + (u << 5)) * NDIM + (lchunk << 2);

  float acc[4][8];
  #pragma unroll
  for (int i = 0; i < 4; ++i)
    #pragma unroll
    for (int j = 0; j < 8; ++j) acc[i][j] = 0.f;

  for (int k0 = 0; k0 < NDIM; k0 += 32){
    float4 av[2], bv[4];
    #pragma unroll
    for (int u = 0; u < 2; ++u) av[u] = *(const float4*)(aptr[u] + k0);
    #pragma unroll
    for (int u = 0; u < 4; ++u) bv[u] = *(const float4*)(bptr[u] + k0);
    __syncthreads();
    #pragma unroll
    for (int u = 0; u < 2; ++u) *(float4*)&As[swz(lrow + (u << 5), lchunk)] = av[u];
    #pragma unroll
    for (int u = 0; u < 4; ++u) *(float4*)&Bs[swz(lrow + (u << 5), lchunk)] = bv[u];
    __syncthreads();
    #pragma unroll
    for (int k4 = 0; k4 < 8; ++k4){
      float4 a4[4];
      #pragma unroll
      for (int i = 0; i < 4; ++i) a4[i] = *(const float4*)&As[swz(ty * 4 + i, k4)];
      #pragma unroll
      for (int j = 0; j < 8; ++j){
        float4 b4 = *(const float4*)&Bs[swz(tx * 8 + j, k4)];
        #pragma unroll
        for (int i = 0; i < 4; ++i)
          acc[i][j] += a4[i].x*b4.x + a4[i].y*b4.y + a4[i].z*b4.z + a4[i].w*b4.w;
      }
    }
  }

  float bl[8];
  #pragma unroll
  for (int j = 0; j < 8; ++j) bl[j] = bias[cbase + (tx << 3) + j];

  #pragma unroll
  for (int i = 0; i < 4; ++i){
    int r = rbase + ty * 4 + i;
    if (r < cnt){
      float* dst = P + ((size_t)b * NSEQ + dstOff + r) * NDIM + cbase + (tx << 3);
      float4 o0, o1;
      o0.x = acc[i][0] + bl[0]; o0.y = acc[i][1] + bl[1];
      o0.z = acc[i][2] + bl[2]; o0.w = acc[i][3] + bl[3];
      o1.x = acc[i][4] + bl[4]; o1.y = acc[i][5] + bl[5];
      o1.z = acc[i][6] + bl[6]; o1.w = acc[i][7] + bl[7];
      *(float4*)dst = o0;
      *(float4*)(dst + 4) = o1;
    }
  }
}

// ---------------- pair phase: logits + |cos| + flash-style tile partials ----
// 32x32 pair tile per block, 4 waves; K=1024 split 256/wave into per-wave
// LDS staging; partial accL/accS published via LDS, then block softmax.
__global__ __launch_bounds__(256)
void k_pair(const float* __restrict__ emb, const float* __restrict__ P,
            const int* __restrict__ idx0, const int* __restrict__ idx1,
            const int* __restrict__ n0a, const int* __restrict__ n1a,
            const float* __restrict__ rnorm, float* __restrict__ partials){
  int b = blockIdx.z;
  int nn0 = n0a[b], nn1 = n1a[b];
  int ibase = blockIdx.x << 5, jbase = blockIdx.y << 5;
  if (nn0 == 0 || nn1 == 0 || ibase >= nn0 || jbase >= nn1) return;

  // per-wave regions: Q[0..1023] K[1024..2047] E[2048..3071] F[3072..4095]
  __shared__ __align__(16) float lds[4][4096];

  int t = threadIdx.x;
  int w = t >> 6, lane = t & 63;
  int tx = lane & 7, ty = lane >> 3;     // compute: 4 cols x 4 rows per lane
  int lr = lane >> 3, lch = lane & 7;    // loader: rows lr+8u, chunk lch
  float* Qs = &lds[w][0];
  float* Ks = &lds[w][1024];
  float* Es = &lds[w][2048];
  float* Fs = &lds[w][3072];

  const float* qptr[4]; const float* kptr[4];
  const float* eptr[4]; const float* fptr[4];
  #pragma unroll
  for (int u = 0; u < 4; ++u){
    int ri = ibase + lr + (u << 3); int ci = min(ri, nn0 - 1);
    int rj = jbase + lr + (u << 3); int cj = min(rj, nn1 - 1);
    qptr[u] = P + ((size_t)b * NSEQ + ci) * NDIM + (lch << 2);
    kptr[u] = P + ((size_t)b * NSEQ + nn0 + cj) * NDIM + (lch << 2);
    eptr[u] = emb + ((size_t)b * NSEQ + idx0[b * NSEQ + ci]) * NDIM + (lch << 2);
    fptr[u] = emb + ((size_t)b * NSEQ + idx1[b * NSEQ + cj]) * NDIM + (lch << 2);
  }

  float accL[4][4], accS[4][4];
  #pragma unroll
  for (int i = 0; i < 4; ++i)
    #pragma unroll
    for (int j = 0; j < 4; ++j){ accL[i][j] = 0.f; accS[i][j] = 0.f; }

  int kbase = w << 8;   // this wave's 256-wide K range
  for (int s = 0; s < 8; ++s){
    int k0 = kbase + (s << 5);
    float4 qv[4], kv[4], ev[4], fv[4];
    #pragma unroll
    for (int u = 0; u < 4; ++u){
      qv[u] = *(const float4*)(qptr[u] + k0);
      kv[u] = *(const float4*)(kptr[u] + k0);
      ev[u] = *(const float4*)(eptr[u] + k0);
      fv[u] = *(const float4*)(fptr[u] + k0);
    }
    __syncthreads();
    #pragma unroll
    for (int u = 0; u < 4; ++u){
      int row = lr + (u << 3);
      *(float4*)&Qs[swz(row, lch)] = qv[u];
      *(float4*)&Ks[swz(row, lch)] = kv[u];
      *(float4*)&Es[swz(row, lch)] = ev[u];
      *(float4*)&Fs[swz(row, lch)] = fv[u];
    }
    __syncthreads();
    #pragma unroll
    for (int k4 = 0; k4 < 8; ++k4){
      float4 q4[4], e4[4];
      #pragma unroll
      for (int i = 0; i < 4; ++i){
        q4[i] = *(const float4*)&Qs[swz(ty * 4 + i, k4)];
        e4[i] = *(const float4*)&Es[swz(ty * 4 + i, k4)];
      }
      #pragma unroll
      for (int j = 0; j < 4; ++j){
        float4 kv4 = *(const float4*)&Ks[swz(tx * 4 + j, k4)];
        float4 fv4 = *(const float4*)&Fs[swz(tx * 4 + j, k4)];
        #pragma unroll
        for (int i = 0; i < 4; ++i){
          accL[i][j] += q4[i].x*kv4.x + q4[i].y*kv4.y + q4[i].z*kv4.z + q4[i].w*kv4.w;
          accS[i][j] += e4[i].x*fv4.x + e4[i].y*fv4.y + e4[i].z*fv4.z + e4[i].w*fv4.w;
        }
      }
    }
  }

  // publish per-wave partial sums (overwrite this wave's Q/K staging)
  __syncthreads();
  #pragma unroll
  for (int i = 0; i < 4; ++i)
    #pragma unroll
    for (int j = 0; j < 4; ++j){
      int l = (ty * 4 + i) * 32 + tx * 4 + j;
      lds[w][l] = accL[i][j];
      lds[w][1024 + l] = accS[i][j];
    }
  __syncthreads();

  // block-wide flattened softmax partials over the 32x32 tile
  float m = NEGBIG, dsum = 0.f, nsum = 0.f;
  #pragma unroll
  for (int u = 0; u < 4; ++u){
    int l = t + (u << 8);
    int i = l >> 5, j = l & 31;
    if ((ibase + i < nn0) && (jbase + j < nn1)){
      float L = lds[0][l] + lds[1][l] + lds[2][l] + lds[3][l];
      float S = lds[0][1024 + l] + lds[1][1024 + l] + lds[2][1024 + l] + lds[3][1024 + l];
      float rnI = rnorm[b * NSEQ + idx0[b * NSEQ + ibase + i]];
      float rnJ = rnorm[b * NSEQ + idx1[b * NSEQ + jbase + j]];
      float mm = fmaxf(m, L);
      float wold = expf(m - mm);
      float e = expf(L - mm);
      dsum = dsum * wold + e;
      nsum = nsum * wold + e * fabsf(S) * rnI * rnJ;
      m = mm;
    }
  }
  #pragma unroll
  for (int off = 1; off < 64; off <<= 1){
    float m2 = __shfl_xor(m, off, 64);
    float d2 = __shfl_xor(dsum, off, 64);
    float s2 = __shfl_xor(nsum, off, 64);
    float mm = fmaxf(m, m2);
    float w1 = expf(m - mm), w2 = expf(m2 - mm);
    dsum = dsum * w1 + d2 * w2;
    nsum = nsum * w1 + s2 * w2;
    m = mm;
  }
  if (lane == 0){
    lds[0][2048 + w * 4 + 0] = m;
    lds[0][2048 + w * 4 + 1] = dsum;
    lds[0][2048 + w * 4 + 2] = nsum;
  }
  __syncthreads();
  if (t == 0){
    float M = NEGBIG, D = 0.f, N = 0.f;
    #pragma unroll
    for (int ww = 0; ww < 4; ++ww){
      float m2 = lds[0][2048 + ww * 4 + 0];
      float d2 = lds[0][2048 + ww * 4 + 1];
      float n2 = lds[0][2048 + ww * 4 + 2];
      float mm = fmaxf(M, m2);
      float w1 = expf(M - mm), w2 = expf(m2 - mm);
      D = D * w1 + d2 * w2;
      N = N * w1 + n2 * w2;
      M = mm;
    }
    float* pp = partials + ((size_t)b * 256 + (blockIdx.x << 4) + blockIdx.y) * 3;
    pp[0] = M; pp[1] = D; pp[2] = N;
  }
}

// ---------------- finalize: merge tile partials per batch ----------------
__global__ __launch_bounds__(64)
void k_final(const float* __restrict__ partials, const int* __restrict__ n0a,
             const int* __restrict__ n1a, float* __restrict__ out){
  int b = blockIdx.x, lane = threadIdx.x;
  int nn0 = n0a[b], nn1 = n1a[b];
  float m = NEGBIG, d = 0.f, n = 0.f;
  if (nn0 > 0 && nn1 > 0){
    int nti = (nn0 + 31) >> 5, ntj = (nn1 + 31) >> 5;
    int cnt = nti * ntj;
    for (int s = lane; s < cnt; s += 64){
      int it = s / ntj, jt = s - it * ntj;
      const float* pp = partials + ((size_t)b * 256 + (it << 4) + jt) * 3;
      float m2 = pp[0], d2 = pp[1], n2 = pp[2];
      float mm = fmaxf(m, m2);
      float w1 = expf(m - mm), w2 = expf(m2 - mm);
      d = d * w1 + d2 * w2;
      n = n * w1 + n2 * w2;
      m = mm;
    }
  }
  #pragma unroll
  for (int off = 1; off < 64; off <<= 1){
    float m2 = __shfl_xor(m, off, 64);
    float d2 = __shfl_xor(d, off, 64);
    float n2 = __shfl_xor(n, off, 64);
    float mm = fmaxf(m, m2);
    float w1 = expf(m - mm), w2 = expf(m2 - mm);
    d = d * w1 + d2 * w2;
    n = n * w1 + n2 * w2;
    m = mm;
  }
  if (lane == 0) out[b] = (d > 0.f) ? (n / d) : 0.f;
}

extern "C" void kernel_launch(void* const* d_in, const int* in_sizes, int n_in,
                              void* d_out, int out_size, void* d_ws, size_t ws_size,
                              hipStream_t stream) {
  const float* emb = (const float*)d_in[0];
  const float* Wq  = (const float*)d_in[1];
  const float* bq  = (const float*)d_in[2];
  const float* Wk  = (const float*)d_in[3];
  const float* bk  = (const float*)d_in[4];
  const int*   am  = (const int*)d_in[5];
  const int*   tt  = (const int*)d_in[6];
  float* out = (float*)d_out;

  char* ws = (char*)d_ws;
  float* P     = (float*)ws;                           // 16*512*1024 f32 = 32 MiB
  int*   idx0  = (int*)(ws + 33554432);                // 16*512 i32
  int*   idx1  = idx0 + NBATCH * NSEQ;
  int*   n0    = idx1 + NBATCH * NSEQ;
  int*   n1    = n0 + NBATCH;
  float* rnorm = (float*)(n1 + NBATCH);                // 16*512 f32
  float* partials = rnorm + NBATCH * NSEQ;             // 16*256*3 f32

  k_compact<<<dim3(NBATCH), dim3(NSEQ), 0, stream>>>(am, tt, idx0, idx1, n0, n1);
  k_rnorm<<<dim3(NBATCH * NSEQ / 4), dim3(256), 0, stream>>>(emb, rnorm);
  // shadow MFMA probe (perf counters only; real k_proj overwrites its output)
  k_proj_mfma<<<dim3(8, 8, NBATCH * 2), dim3(256), 0, stream>>>(emb, Wq, bq, Wk, bk,
                                                                idx0, idx1, n0, n1, P);
  k_proj<<<dim3(8, 8, NBATCH * 2), dim3(256), 0, stream>>>(emb, Wq, bq, Wk, bk,
                                                           idx0, idx1, n0, n1, P);
  k_pair<<<dim3(16, 16, NBATCH), dim3(256), 0, stream>>>(emb, P, idx0, idx1,
                                                         n0, n1, rnorm, partials);
  k_final<<<dim3(NBATCH), dim3(64), 0, stream>>>(partials, n0, n1, out);
}

// Round 9
// 332.119 us; speedup vs baseline: 15.2380x; 5.8291x over previous
//
#include <hip/hip_runtime.h>
#include <math.h>

#define NBATCH 16
#define NSEQ   512
#define NDIM   1024
#define NEGBIG (-1e30f)

typedef __attribute__((ext_vector_type(8))) short bf16x8;
typedef __attribute__((ext_vector_type(8))) unsigned short u16x8;
typedef __attribute__((ext_vector_type(4))) float f32x4;

// LDS row stride for 32-bf16 (64B) tile rows: 80B (odd multiple of 16B).
// Bank-quad of row r chunk c = (5r + c) % 8 -> 16-row fragment reads at fixed
// chunk touch all 8 quads (2-way max aliasing = free per m136).
#define LROW 80

// f32 -> bf16 hi (truncate) + bf16 lo (exact residual, truncated).
__device__ __forceinline__ void split1(float f, unsigned short& h, unsigned short& l){
  unsigned u = __float_as_uint(f);
  h = (unsigned short)(u >> 16);
  float fl = f - __uint_as_float(u & 0xffff0000u);
  l = (unsigned short)(__float_as_uint(fl) >> 16);
}

// ---------------- mask compaction ----------------
__global__ __launch_bounds__(512)
void k_compact(const int* __restrict__ am, const int* __restrict__ tt,
               int* __restrict__ idx0, int* __restrict__ idx1,
               int* __restrict__ n0, int* __restrict__ n1){
  int b = blockIdx.x, t = threadIdx.x;
  int a = am[b * NSEQ + t];
  int y = tt[b * NSEQ + t];
  bool p0 = (a == 1) && (y == 0);
  bool p1 = (a == 1) && (y == 1);
  __shared__ int wc0[8], wc1[8], wo0[8], wo1[8];
  int wave = t >> 6, lane = t & 63;
  unsigned long long m0 = __ballot(p0);
  unsigned long long m1 = __ballot(p1);
  unsigned long long below = (1ULL << lane) - 1ULL;
  int r0 = __popcll(m0 & below);
  int r1 = __popcll(m1 & below);
  if (lane == 0){ wc0[wave] = __popcll(m0); wc1[wave] = __popcll(m1); }
  __syncthreads();
  if (t == 0){
    int s0 = 0, s1 = 0;
    for (int w = 0; w < 8; ++w){ wo0[w] = s0; s0 += wc0[w]; wo1[w] = s1; s1 += wc1[w]; }
    n0[b] = s0; n1[b] = s1;
  }
  __syncthreads();
  if (p0) idx0[b * NSEQ + wo0[wave] + r0] = t;
  if (p1) idx1[b * NSEQ + wo1[wave] + r1] = t;
}

// ---------------- per-row 1/max(||x||,eps) ----------------
__global__ __launch_bounds__(256)
void k_rnorm(const float* __restrict__ emb, float* __restrict__ rnorm){
  int wave = threadIdx.x >> 6, lane = threadIdx.x & 63;
  int row = blockIdx.x * 4 + wave;
  const float4* p = (const float4*)(emb + (size_t)row * NDIM);
  float ss = 0.f;
  #pragma unroll
  for (int i = 0; i < 4; ++i){
    float4 v = p[i * 64 + lane];
    ss += v.x*v.x + v.y*v.y + v.z*v.z + v.w*v.w;
  }
  #pragma unroll
  for (int off = 32; off > 0; off >>= 1) ss += __shfl_down(ss, off, 64);
  if (lane == 0) rnorm[row] = 1.f / fmaxf(sqrtf(ss), 1e-12f);
}

// ---------------- f32 -> bf16 hi/lo pre-conversion ----------------
__global__ __launch_bounds__(256)
void k_conv(const float* __restrict__ src, unsigned short* __restrict__ hi,
            unsigned short* __restrict__ lo, int n8){
  int t = blockIdx.x * 256 + threadIdx.x;
  if (t >= n8) return;
  const float4* s = (const float4*)(src + (size_t)t * 8);
  float4 a = s[0], b = s[1];
  float v[8] = {a.x, a.y, a.z, a.w, b.x, b.y, b.z, b.w};
  u16x8 h, l;
  #pragma unroll
  for (int i = 0; i < 8; ++i){
    unsigned short hh, ll; split1(v[i], hh, ll); h[i] = hh; l[i] = ll;
  }
  *(u16x8*)(hi + (size_t)t * 8) = h;
  *(u16x8*)(lo + (size_t)t * 8) = l;
}

// ---------------- MFMA projection GEMM (bf16 3-pass hi/lo split) ----------
// 256 threads / 4 waves; block tile 64(M) x 128(N), BK=32; wave quadrant
// 32x64 = 2(fm) x 4(fn) 16x16 frags. Writes P as bf16 hi/lo for k_pair.
__global__ __launch_bounds__(256)
void k_proj(const unsigned short* __restrict__ Eh, const unsigned short* __restrict__ El,
            const unsigned short* __restrict__ Wqh, const unsigned short* __restrict__ Wql,
            const unsigned short* __restrict__ Wkh, const unsigned short* __restrict__ Wkl,
            const float* __restrict__ bq, const float* __restrict__ bk,
            const int* __restrict__ idx0, const int* __restrict__ idx1,
            const int* __restrict__ n0, const int* __restrict__ n1,
            unsigned short* __restrict__ Ph, unsigned short* __restrict__ Pl){
  int z = blockIdx.z;
  int b = z >> 1, which = z & 1;
  int cnt = which ? n1[b] : n0[b];
  int rbase = blockIdx.x << 6;
  if (cnt == 0 || rbase >= cnt) return;
  const unsigned short* __restrict__ Wh = which ? Wkh : Wqh;
  const unsigned short* __restrict__ Wl = which ? Wkl : Wql;
  const float* __restrict__ bias = which ? bk : bq;
  const int*   __restrict__ idx  = (which ? idx1 : idx0) + b * NSEQ;
  int dstOff = which ? n0[b] : 0;
  int cbase = blockIdx.y << 7;

  __shared__ __align__(16) char Ah[64 * LROW], Al[64 * LROW];
  __shared__ __align__(16) char Bh[128 * LROW], Bl[128 * LROW];

  int t = threadIdx.x;
  int w = t >> 6, lane = t & 63;
  int wm = w >> 1, wn = w & 1;
  int fr = lane & 15, kg = lane >> 4;

  // staging: A = 64 rows x 4 16B-chunks (1/thread); B = 128 rows (2/thread)
  int srow = t >> 2, schk = t & 3;
  int ar = min(rbase + srow, cnt - 1);
  size_t aoff = ((size_t)b * NSEQ + idx[ar]) * NDIM + schk * 8;
  const unsigned short* aSh = Eh + aoff;
  const unsigned short* aSl = El + aoff;
  const unsigned short* bSh0 = Wh + (size_t)(cbase + srow) * NDIM + schk * 8;
  const unsigned short* bSl0 = Wl + (size_t)(cbase + srow) * NDIM + schk * 8;
  const unsigned short* bSh1 = Wh + (size_t)(cbase + srow + 64) * NDIM + schk * 8;
  const unsigned short* bSl1 = Wl + (size_t)(cbase + srow + 64) * NDIM + schk * 8;
  char* aDh = Ah + srow * LROW + schk * 16;
  char* aDl = Al + srow * LROW + schk * 16;
  char* bDh0 = Bh + srow * LROW + schk * 16;
  char* bDl0 = Bl + srow * LROW + schk * 16;
  char* bDh1 = Bh + (srow + 64) * LROW + schk * 16;
  char* bDl1 = Bl + (srow + 64) * LROW + schk * 16;

  f32x4 acc[2][4];
  #pragma unroll
  for (int i = 0; i < 2; ++i)
    #pragma unroll
    for (int j = 0; j < 4; ++j) acc[i][j] = (f32x4){0.f, 0.f, 0.f, 0.f};

  for (int k0 = 0; k0 < NDIM; k0 += 32){
    uint4 v0 = *(const uint4*)(aSh + k0);
    uint4 v1 = *(const uint4*)(aSl + k0);
    uint4 v2 = *(const uint4*)(bSh0 + k0);
    uint4 v3 = *(const uint4*)(bSl0 + k0);
    uint4 v4 = *(const uint4*)(bSh1 + k0);
    uint4 v5 = *(const uint4*)(bSl1 + k0);
    __syncthreads();
    *(uint4*)aDh = v0;  *(uint4*)aDl = v1;
    *(uint4*)bDh0 = v2; *(uint4*)bDl0 = v3;
    *(uint4*)bDh1 = v4; *(uint4*)bDl1 = v5;
    __syncthreads();

    bf16x8 ah[2], al_[2], bh[4], bl_[4];
    #pragma unroll
    for (int fm = 0; fm < 2; ++fm){
      int r = wm * 32 + fm * 16 + fr;
      ah[fm]  = *(const bf16x8*)(Ah + r * LROW + kg * 16);
      al_[fm] = *(const bf16x8*)(Al + r * LROW + kg * 16);
    }
    #pragma unroll
    for (int fn = 0; fn < 4; ++fn){
      int r = wn * 64 + fn * 16 + fr;
      bh[fn]  = *(const bf16x8*)(Bh + r * LROW + kg * 16);
      bl_[fn] = *(const bf16x8*)(Bl + r * LROW + kg * 16);
    }
    #pragma unroll
    for (int fm = 0; fm < 2; ++fm)
      #pragma unroll
      for (int fn = 0; fn < 4; ++fn){
        acc[fm][fn] = __builtin_amdgcn_mfma_f32_16x16x32_bf16(ah[fm], bh[fn], acc[fm][fn], 0, 0, 0);
        acc[fm][fn] = __builtin_amdgcn_mfma_f32_16x16x32_bf16(ah[fm], bl_[fn], acc[fm][fn], 0, 0, 0);
        acc[fm][fn] = __builtin_amdgcn_mfma_f32_16x16x32_bf16(al_[fm], bh[fn], acc[fm][fn], 0, 0, 0);
      }
  }

  // C/D layout (m89-verified): col = lane&15, row = (lane>>4)*4 + reg
  #pragma unroll
  for (int fm = 0; fm < 2; ++fm)
    #pragma unroll
    for (int fn = 0; fn < 4; ++fn)
      #pragma unroll
      for (int reg = 0; reg < 4; ++reg){
        int rloc = wm * 32 + fm * 16 + (kg << 2) + reg;
        if (rbase + rloc < cnt){
          int gc = cbase + wn * 64 + fn * 16 + fr;
          float v = acc[fm][fn][reg] + bias[gc];
          unsigned short h, l; split1(v, h, l);
          size_t o = ((size_t)b * NSEQ + dstOff + rbase + rloc) * NDIM + gc;
          Ph[o] = h; Pl[o] = l;
        }
      }
}

// ---------------- pair phase: MFMA logits + |cos| + tile softmax partials --
// 32x32 pair tile; 4 waves each own a 16x16 quadrant (ih,jh); shared staged
// Q/K/E/F hi/lo k-slices (BK=32); two GEMMs (L = q.k, S = e.e) 3-pass each.
__global__ __launch_bounds__(256)
void k_pair(const unsigned short* __restrict__ Ph, const unsigned short* __restrict__ Pl,
            const unsigned short* __restrict__ Eh, const unsigned short* __restrict__ El,
            const int* __restrict__ idx0, const int* __restrict__ idx1,
            const int* __restrict__ n0a, const int* __restrict__ n1a,
            const float* __restrict__ rnorm, float* __restrict__ partials){
  int b = blockIdx.z;
  int nn0 = n0a[b], nn1 = n1a[b];
  int ibase = blockIdx.x << 5, jbase = blockIdx.y << 5;
  if (nn0 == 0 || nn1 == 0 || ibase >= nn0 || jbase >= nn1) return;

  __shared__ __align__(16) char stage[8 * 32 * LROW];  // Qh Ql Kh Kl Eh El Fh Fl
  __shared__ __align__(16) float Lout[1024];
  __shared__ __align__(16) float Sout[1024];
  __shared__ float red[12];

  int t = threadIdx.x;
  int w = t >> 6, lane = t & 63;
  int ih = w >> 1, jh = w & 1;
  int fr = lane & 15, kg = lane >> 4;

  // staging: tile = t>>5 (8 tiles), row = t&31, 4 chunks (64B) per thread
  int tile = t >> 5, srow = t & 31;
  const unsigned short* src;
  {
    int ci = min(ibase + srow, nn0 - 1);
    int cj = min(jbase + srow, nn1 - 1);
    const unsigned short* hb; size_t r;
    switch (tile){
      case 0: hb = Ph; r = (size_t)b * NSEQ + ci; break;
      case 1: hb = Pl; r = (size_t)b * NSEQ + ci; break;
      case 2: hb = Ph; r = (size_t)b * NSEQ + nn0 + cj; break;
      case 3: hb = Pl; r = (size_t)b * NSEQ + nn0 + cj; break;
      case 4: hb = Eh; r = (size_t)b * NSEQ + idx0[b * NSEQ + ci]; break;
      case 5: hb = El; r = (size_t)b * NSEQ + idx0[b * NSEQ + ci]; break;
      case 6: hb = Eh; r = (size_t)b * NSEQ + idx1[b * NSEQ + cj]; break;
      default: hb = El; r = (size_t)b * NSEQ + idx1[b * NSEQ + cj]; break;
    }
    src = hb + r * NDIM;
  }
  char* dst = stage + tile * (32 * LROW) + srow * LROW;
  char* Qh_ = stage;
  char* Ql_ = stage + 1 * (32 * LROW);
  char* Kh_ = stage + 2 * (32 * LROW);
  char* Kl_ = stage + 3 * (32 * LROW);
  char* Eh_ = stage + 4 * (32 * LROW);
  char* El_ = stage + 5 * (32 * LROW);
  char* Fh_ = stage + 6 * (32 * LROW);
  char* Fl_ = stage + 7 * (32 * LROW);

  f32x4 accL = (f32x4){0.f, 0.f, 0.f, 0.f};
  f32x4 accS = (f32x4){0.f, 0.f, 0.f, 0.f};
  int qrow = ih * 16 + fr, krow = jh * 16 + fr;

  for (int k0 = 0; k0 < NDIM; k0 += 32){
    uint4 v0 = *(const uint4*)(src + k0);
    uint4 v1 = *(const uint4*)(src + k0 + 8);
    uint4 v2 = *(const uint4*)(src + k0 + 16);
    uint4 v3 = *(const uint4*)(src + k0 + 24);
    __syncthreads();
    *(uint4*)(dst)      = v0;
    *(uint4*)(dst + 16) = v1;
    *(uint4*)(dst + 32) = v2;
    *(uint4*)(dst + 48) = v3;
    __syncthreads();

    bf16x8 qh = *(const bf16x8*)(Qh_ + qrow * LROW + kg * 16);
    bf16x8 ql = *(const bf16x8*)(Ql_ + qrow * LROW + kg * 16);
    bf16x8 kh = *(const bf16x8*)(Kh_ + krow * LROW + kg * 16);
    bf16x8 kl = *(const bf16x8*)(Kl_ + krow * LROW + kg * 16);
    bf16x8 eh = *(const bf16x8*)(Eh_ + qrow * LROW + kg * 16);
    bf16x8 el = *(const bf16x8*)(El_ + qrow * LROW + kg * 16);
    bf16x8 fh = *(const bf16x8*)(Fh_ + krow * LROW + kg * 16);
    bf16x8 fl = *(const bf16x8*)(Fl_ + krow * LROW + kg * 16);

    accL = __builtin_amdgcn_mfma_f32_16x16x32_bf16(qh, kh, accL, 0, 0, 0);
    accL = __builtin_amdgcn_mfma_f32_16x16x32_bf16(qh, kl, accL, 0, 0, 0);
    accL = __builtin_amdgcn_mfma_f32_16x16x32_bf16(ql, kh, accL, 0, 0, 0);
    accS = __builtin_amdgcn_mfma_f32_16x16x32_bf16(eh, fh, accS, 0, 0, 0);
    accS = __builtin_amdgcn_mfma_f32_16x16x32_bf16(eh, fl, accS, 0, 0, 0);
    accS = __builtin_amdgcn_mfma_f32_16x16x32_bf16(el, fh, accS, 0, 0, 0);
  }

  __syncthreads();
  #pragma unroll
  for (int reg = 0; reg < 4; ++reg){
    int li = ih * 16 + (kg << 2) + reg, lj = jh * 16 + fr;
    Lout[li * 32 + lj] = accL[reg];
    Sout[li * 32 + lj] = accS[reg];
  }
  __syncthreads();

  // block-wide flattened softmax partials over the 32x32 tile
  float m = NEGBIG, dsum = 0.f, nsum = 0.f;
  #pragma unroll
  for (int u = 0; u < 4; ++u){
    int l = t + (u << 8);
    int i = l >> 5, j = l & 31;
    if ((ibase + i < nn0) && (jbase + j < nn1)){
      float L = Lout[l];
      float S = Sout[l];
      float rnI = rnorm[b * NSEQ + idx0[b * NSEQ + ibase + i]];
      float rnJ = rnorm[b * NSEQ + idx1[b * NSEQ + jbase + j]];
      float mm = fmaxf(m, L);
      float wold = expf(m - mm);
      float e = expf(L - mm);
      dsum = dsum * wold + e;
      nsum = nsum * wold + e * fabsf(S) * rnI * rnJ;
      m = mm;
    }
  }
  #pragma unroll
  for (int off = 1; off < 64; off <<= 1){
    float m2 = __shfl_xor(m, off, 64);
    float d2 = __shfl_xor(dsum, off, 64);
    float s2 = __shfl_xor(nsum, off, 64);
    float mm = fmaxf(m, m2);
    float w1 = expf(m - mm), w2 = expf(m2 - mm);
    dsum = dsum * w1 + d2 * w2;
    nsum = nsum * w1 + s2 * w2;
    m = mm;
  }
  if (lane == 0){ red[w * 3 + 0] = m; red[w * 3 + 1] = dsum; red[w * 3 + 2] = nsum; }
  __syncthreads();
  if (t == 0){
    float M = NEGBIG, D = 0.f, N = 0.f;
    #pragma unroll
    for (int ww = 0; ww < 4; ++ww){
      float m2 = red[ww * 3 + 0], d2 = red[ww * 3 + 1], n2 = red[ww * 3 + 2];
      float mm = fmaxf(M, m2);
      float w1 = expf(M - mm), w2 = expf(m2 - mm);
      D = D * w1 + d2 * w2;
      N = N * w1 + n2 * w2;
      M = mm;
    }
    float* pp = partials + ((size_t)b * 256 + (blockIdx.x << 4) + blockIdx.y) * 3;
    pp[0] = M; pp[1] = D; pp[2] = N;
  }
}

// ---------------- finalize: merge tile partials per batch ----------------
__global__ __launch_bounds__(64)
void k_final(const float* __restrict__ partials, const int* __restrict__ n0a,
             const int* __restrict__ n1a, float* __restrict__ out){
  int b = blockIdx.x, lane = threadIdx.x;
  int nn0 = n0a[b], nn1 = n1a[b];
  float m = NEGBIG, d = 0.f, n = 0.f;
  if (nn0 > 0 && nn1 > 0){
    int nti = (nn0 + 31) >> 5, ntj = (nn1 + 31) >> 5;
    int cnt = nti * ntj;
    for (int s = lane; s < cnt; s += 64){
      int it = s / ntj, jt = s - it * ntj;
      const float* pp = partials + ((size_t)b * 256 + (it << 4) + jt) * 3;
      float m2 = pp[0], d2 = pp[1], n2 = pp[2];
      float mm = fmaxf(m, m2);
      float w1 = expf(m - mm), w2 = expf(m2 - mm);
      d = d * w1 + d2 * w2;
      n = n * w1 + n2 * w2;
      m = mm;
    }
  }
  #pragma unroll
  for (int off = 1; off < 64; off <<= 1){
    float m2 = __shfl_xor(m, off, 64);
    float d2 = __shfl_xor(d, off, 64);
    float n2 = __shfl_xor(n, off, 64);
    float mm = fmaxf(m, m2);
    float w1 = expf(m - mm), w2 = expf(m2 - mm);
    d = d * w1 + d2 * w2;
    n = n * w1 + n2 * w2;
    m = mm;
  }
  if (lane == 0) out[b] = (d > 0.f) ? (n / d) : 0.f;
}

extern "C" void kernel_launch(void* const* d_in, const int* in_sizes, int n_in,
                              void* d_out, int out_size, void* d_ws, size_t ws_size,
                              hipStream_t stream) {
  const float* emb = (const float*)d_in[0];
  const float* Wq  = (const float*)d_in[1];
  const float* bq  = (const float*)d_in[2];
  const float* Wk  = (const float*)d_in[3];
  const float* bk  = (const float*)d_in[4];
  const int*   am  = (const int*)d_in[5];
  const int*   tt  = (const int*)d_in[6];
  float* out = (float*)d_out;

  // workspace layout (~72.2 MB)
  char* ws = (char*)d_ws;
  unsigned short* Eh  = (unsigned short*)(ws);                        // 16 MB
  unsigned short* El  = (unsigned short*)(ws + (1u << 24));           // 16 MB
  unsigned short* Ph  = (unsigned short*)(ws + 2u * (1u << 24));      // 16 MB
  unsigned short* Pl  = (unsigned short*)(ws + 3u * (1u << 24));      // 16 MB
  unsigned short* Wqh = (unsigned short*)(ws + 4u * (1u << 24));      // 2 MB
  unsigned short* Wql = (unsigned short*)(ws + 4u * (1u << 24) + 1u * (1u << 21));
  unsigned short* Wkh = (unsigned short*)(ws + 4u * (1u << 24) + 2u * (1u << 21));
  unsigned short* Wkl = (unsigned short*)(ws + 4u * (1u << 24) + 3u * (1u << 21));
  char* misc = ws + 4u * (1u << 24) + 4u * (1u << 21);
  int*   idx0  = (int*)misc;
  int*   idx1  = idx0 + NBATCH * NSEQ;
  int*   n0    = idx1 + NBATCH * NSEQ;
  int*   n1    = n0 + NBATCH;
  float* rnorm = (float*)(n1 + NBATCH);
  float* partials = rnorm + NBATCH * NSEQ;

  k_compact<<<dim3(NBATCH), dim3(NSEQ), 0, stream>>>(am, tt, idx0, idx1, n0, n1);
  k_rnorm<<<dim3(NBATCH * NSEQ / 4), dim3(256), 0, stream>>>(emb, rnorm);
  k_conv<<<dim3(4096), dim3(256), 0, stream>>>(emb, Eh, El, NBATCH * NSEQ * NDIM / 8);
  k_conv<<<dim3(512), dim3(256), 0, stream>>>(Wq, Wqh, Wql, NDIM * NDIM / 8);
  k_conv<<<dim3(512), dim3(256), 0, stream>>>(Wk, Wkh, Wkl, NDIM * NDIM / 8);
  k_proj<<<dim3(8, 8, NBATCH * 2), dim3(256), 0, stream>>>(Eh, El, Wqh, Wql, Wkh, Wkl,
                                                           bq, bk, idx0, idx1, n0, n1, Ph, Pl);
  k_pair<<<dim3(16, 16, NBATCH), dim3(256), 0, stream>>>(Ph, Pl, Eh, El, idx0, idx1,
                                                         n0, n1, rnorm, partials);
  k_final<<<dim3(NBATCH), dim3(64), 0, stream>>>(partials, n0, n1, out);
}

// Round 10
// 323.948 us; speedup vs baseline: 15.6223x; 1.0252x over previous
//
#include <hip/hip_runtime.h>
#include <math.h>

#define NBATCH 16
#define NSEQ   512
#define NDIM   1024
#define NEGBIG (-1e30f)

typedef __attribute__((ext_vector_type(8))) short bf16x8;
typedef __attribute__((ext_vector_type(8))) unsigned short u16x8;
typedef __attribute__((ext_vector_type(4))) float f32x4;

// LDS row stride for 32-bf16 (64B) tile rows: 80B (odd multiple of 16B).
// Bank-quad of row r chunk c = (5r + c) % 8 -> 16-row fragment reads at fixed
// chunk touch all 8 quads (2-way max aliasing = free per m136).
#define LROW 80

// f32 -> bf16 hi (truncate) + bf16 lo (exact residual, truncated).
__device__ __forceinline__ void split1(float f, unsigned short& h, unsigned short& l){
  unsigned u = __float_as_uint(f);
  h = (unsigned short)(u >> 16);
  float fl = f - __uint_as_float(u & 0xffff0000u);
  l = (unsigned short)(__float_as_uint(fl) >> 16);
}

// ---------------- mask compaction ----------------
__global__ __launch_bounds__(512)
void k_compact(const int* __restrict__ am, const int* __restrict__ tt,
               int* __restrict__ idx0, int* __restrict__ idx1,
               int* __restrict__ n0, int* __restrict__ n1){
  int b = blockIdx.x, t = threadIdx.x;
  int a = am[b * NSEQ + t];
  int y = tt[b * NSEQ + t];
  bool p0 = (a == 1) && (y == 0);
  bool p1 = (a == 1) && (y == 1);
  __shared__ int wc0[8], wc1[8], wo0[8], wo1[8];
  int wave = t >> 6, lane = t & 63;
  unsigned long long m0 = __ballot(p0);
  unsigned long long m1 = __ballot(p1);
  unsigned long long below = (1ULL << lane) - 1ULL;
  int r0 = __popcll(m0 & below);
  int r1 = __popcll(m1 & below);
  if (lane == 0){ wc0[wave] = __popcll(m0); wc1[wave] = __popcll(m1); }
  __syncthreads();
  if (t == 0){
    int s0 = 0, s1 = 0;
    for (int w = 0; w < 8; ++w){ wo0[w] = s0; s0 += wc0[w]; wo1[w] = s1; s1 += wc1[w]; }
    n0[b] = s0; n1[b] = s1;
  }
  __syncthreads();
  if (p0) idx0[b * NSEQ + wo0[wave] + r0] = t;
  if (p1) idx1[b * NSEQ + wo1[wave] + r1] = t;
}

// ---------------- per-row 1/max(||x||,eps) ----------------
__global__ __launch_bounds__(256)
void k_rnorm(const float* __restrict__ emb, float* __restrict__ rnorm){
  int wave = threadIdx.x >> 6, lane = threadIdx.x & 63;
  int row = blockIdx.x * 4 + wave;
  const float4* p = (const float4*)(emb + (size_t)row * NDIM);
  float ss = 0.f;
  #pragma unroll
  for (int i = 0; i < 4; ++i){
    float4 v = p[i * 64 + lane];
    ss += v.x*v.x + v.y*v.y + v.z*v.z + v.w*v.w;
  }
  #pragma unroll
  for (int off = 32; off > 0; off >>= 1) ss += __shfl_down(ss, off, 64);
  if (lane == 0) rnorm[row] = 1.f / fmaxf(sqrtf(ss), 1e-12f);
}

// ---------------- f32 -> bf16 hi/lo pre-conversion ----------------
__global__ __launch_bounds__(256)
void k_conv(const float* __restrict__ src, unsigned short* __restrict__ hi,
            unsigned short* __restrict__ lo, int n8){
  int t = blockIdx.x * 256 + threadIdx.x;
  if (t >= n8) return;
  const float4* s = (const float4*)(src + (size_t)t * 8);
  float4 a = s[0], b = s[1];
  float v[8] = {a.x, a.y, a.z, a.w, b.x, b.y, b.z, b.w};
  u16x8 h, l;
  #pragma unroll
  for (int i = 0; i < 8; ++i){
    unsigned short hh, ll; split1(v[i], hh, ll); h[i] = hh; l[i] = ll;
  }
  *(u16x8*)(hi + (size_t)t * 8) = h;
  *(u16x8*)(lo + (size_t)t * 8) = l;
}

// ---------------- MFMA projection GEMM (bf16 3-pass hi/lo split) ----------
// 256 threads / 4 waves; block tile 64(M) x 128(N), BK=32; wave quadrant
// 32x64 = 2(fm) x 4(fn) 16x16 frags. Software-pipelined: K-step i+1's global
// loads are issued BEFORE step i's MFMA cluster (latency hides under compute).
__global__ __launch_bounds__(256)
void k_proj(const unsigned short* __restrict__ Eh, const unsigned short* __restrict__ El,
            const unsigned short* __restrict__ Wqh, const unsigned short* __restrict__ Wql,
            const unsigned short* __restrict__ Wkh, const unsigned short* __restrict__ Wkl,
            const float* __restrict__ bq, const float* __restrict__ bk,
            const int* __restrict__ idx0, const int* __restrict__ idx1,
            const int* __restrict__ n0, const int* __restrict__ n1,
            unsigned short* __restrict__ Ph, unsigned short* __restrict__ Pl){
  int z = blockIdx.z;
  int b = z >> 1, which = z & 1;
  int cnt = which ? n1[b] : n0[b];
  int rbase = blockIdx.x << 6;
  if (cnt == 0 || rbase >= cnt) return;
  const unsigned short* __restrict__ Wh = which ? Wkh : Wqh;
  const unsigned short* __restrict__ Wl = which ? Wkl : Wql;
  const float* __restrict__ bias = which ? bk : bq;
  const int*   __restrict__ idx  = (which ? idx1 : idx0) + b * NSEQ;
  int dstOff = which ? n0[b] : 0;
  int cbase = blockIdx.y << 7;

  __shared__ __align__(16) char Ah[64 * LROW], Al[64 * LROW];
  __shared__ __align__(16) char Bh[128 * LROW], Bl[128 * LROW];

  int t = threadIdx.x;
  int w = t >> 6, lane = t & 63;
  int wm = w >> 1, wn = w & 1;
  int fr = lane & 15, kg = lane >> 4;

  // staging: A = 64 rows x 4 16B-chunks (1/thread); B = 128 rows (2/thread)
  int srow = t >> 2, schk = t & 3;
  int ar = min(rbase + srow, cnt - 1);
  size_t aoff = ((size_t)b * NSEQ + idx[ar]) * NDIM + schk * 8;
  const unsigned short* aSh = Eh + aoff;
  const unsigned short* aSl = El + aoff;
  const unsigned short* bSh0 = Wh + (size_t)(cbase + srow) * NDIM + schk * 8;
  const unsigned short* bSl0 = Wl + (size_t)(cbase + srow) * NDIM + schk * 8;
  const unsigned short* bSh1 = Wh + (size_t)(cbase + srow + 64) * NDIM + schk * 8;
  const unsigned short* bSl1 = Wl + (size_t)(cbase + srow + 64) * NDIM + schk * 8;
  char* aDh = Ah + srow * LROW + schk * 16;
  char* aDl = Al + srow * LROW + schk * 16;
  char* bDh0 = Bh + srow * LROW + schk * 16;
  char* bDl0 = Bl + srow * LROW + schk * 16;
  char* bDh1 = Bh + (srow + 64) * LROW + schk * 16;
  char* bDl1 = Bl + (srow + 64) * LROW + schk * 16;

  f32x4 acc[2][4];
  #pragma unroll
  for (int i = 0; i < 2; ++i)
    #pragma unroll
    for (int j = 0; j < 4; ++j) acc[i][j] = (f32x4){0.f, 0.f, 0.f, 0.f};

  // prologue: load K-step 0
  uint4 v0 = *(const uint4*)(aSh);
  uint4 v1 = *(const uint4*)(aSl);
  uint4 v2 = *(const uint4*)(bSh0);
  uint4 v3 = *(const uint4*)(bSl0);
  uint4 v4 = *(const uint4*)(bSh1);
  uint4 v5 = *(const uint4*)(bSl1);

  for (int k0 = 0; k0 < NDIM; k0 += 32){
    __syncthreads();
    *(uint4*)aDh = v0;  *(uint4*)aDl = v1;
    *(uint4*)bDh0 = v2; *(uint4*)bDl0 = v3;
    *(uint4*)bDh1 = v4; *(uint4*)bDl1 = v5;
    __syncthreads();

    // prefetch K-step k0+32 BEFORE the MFMA cluster (hide load latency)
    int kn = k0 + 32;
    if (kn < NDIM){
      v0 = *(const uint4*)(aSh + kn);
      v1 = *(const uint4*)(aSl + kn);
      v2 = *(const uint4*)(bSh0 + kn);
      v3 = *(const uint4*)(bSl0 + kn);
      v4 = *(const uint4*)(bSh1 + kn);
      v5 = *(const uint4*)(bSl1 + kn);
    }

    bf16x8 ah[2], al_[2], bh[4], bl_[4];
    #pragma unroll
    for (int fm = 0; fm < 2; ++fm){
      int r = wm * 32 + fm * 16 + fr;
      ah[fm]  = *(const bf16x8*)(Ah + r * LROW + kg * 16);
      al_[fm] = *(const bf16x8*)(Al + r * LROW + kg * 16);
    }
    #pragma unroll
    for (int fn = 0; fn < 4; ++fn){
      int r = wn * 64 + fn * 16 + fr;
      bh[fn]  = *(const bf16x8*)(Bh + r * LROW + kg * 16);
      bl_[fn] = *(const bf16x8*)(Bl + r * LROW + kg * 16);
    }
    #pragma unroll
    for (int fm = 0; fm < 2; ++fm)
      #pragma unroll
      for (int fn = 0; fn < 4; ++fn){
        acc[fm][fn] = __builtin_amdgcn_mfma_f32_16x16x32_bf16(ah[fm], bh[fn], acc[fm][fn], 0, 0, 0);
        acc[fm][fn] = __builtin_amdgcn_mfma_f32_16x16x32_bf16(ah[fm], bl_[fn], acc[fm][fn], 0, 0, 0);
        acc[fm][fn] = __builtin_amdgcn_mfma_f32_16x16x32_bf16(al_[fm], bh[fn], acc[fm][fn], 0, 0, 0);
      }
  }

  // C/D layout (m89-verified): col = lane&15, row = (lane>>4)*4 + reg
  #pragma unroll
  for (int fm = 0; fm < 2; ++fm)
    #pragma unroll
    for (int fn = 0; fn < 4; ++fn)
      #pragma unroll
      for (int reg = 0; reg < 4; ++reg){
        int rloc = wm * 32 + fm * 16 + (kg << 2) + reg;
        if (rbase + rloc < cnt){
          int gc = cbase + wn * 64 + fn * 16 + fr;
          float v = acc[fm][fn][reg] + bias[gc];
          unsigned short h, l; split1(v, h, l);
          size_t o = ((size_t)b * NSEQ + dstOff + rbase + rloc) * NDIM + gc;
          Ph[o] = h; Pl[o] = l;
        }
      }
}

// ---------------- pair phase: MFMA logits + |cos| + tile softmax partials --
// 32x32 pair tile; 4 waves each own a 16x16 quadrant (ih,jh); shared staged
// Q/K/E/F hi/lo k-slices (BK=32); two GEMMs (L = q.k, S = e.e) 3-pass each.
// Software-pipelined staging like k_proj.
__global__ __launch_bounds__(256)
void k_pair(const unsigned short* __restrict__ Ph, const unsigned short* __restrict__ Pl,
            const unsigned short* __restrict__ Eh, const unsigned short* __restrict__ El,
            const int* __restrict__ idx0, const int* __restrict__ idx1,
            const int* __restrict__ n0a, const int* __restrict__ n1a,
            const float* __restrict__ rnorm, float* __restrict__ partials){
  int b = blockIdx.z;
  int nn0 = n0a[b], nn1 = n1a[b];
  int ibase = blockIdx.x << 5, jbase = blockIdx.y << 5;
  if (nn0 == 0 || nn1 == 0 || ibase >= nn0 || jbase >= nn1) return;

  __shared__ __align__(16) char stage[8 * 32 * LROW];  // Qh Ql Kh Kl Eh El Fh Fl
  __shared__ __align__(16) float Lout[1024];
  __shared__ __align__(16) float Sout[1024];
  __shared__ float red[12];

  int t = threadIdx.x;
  int w = t >> 6, lane = t & 63;
  int ih = w >> 1, jh = w & 1;
  int fr = lane & 15, kg = lane >> 4;

  // staging: tile = t>>5 (8 tiles), row = t&31, 4 chunks (64B) per thread
  int tile = t >> 5, srow = t & 31;
  const unsigned short* src;
  {
    int ci = min(ibase + srow, nn0 - 1);
    int cj = min(jbase + srow, nn1 - 1);
    const unsigned short* hb; size_t r;
    switch (tile){
      case 0: hb = Ph; r = (size_t)b * NSEQ + ci; break;
      case 1: hb = Pl; r = (size_t)b * NSEQ + ci; break;
      case 2: hb = Ph; r = (size_t)b * NSEQ + nn0 + cj; break;
      case 3: hb = Pl; r = (size_t)b * NSEQ + nn0 + cj; break;
      case 4: hb = Eh; r = (size_t)b * NSEQ + idx0[b * NSEQ + ci]; break;
      case 5: hb = El; r = (size_t)b * NSEQ + idx0[b * NSEQ + ci]; break;
      case 6: hb = Eh; r = (size_t)b * NSEQ + idx1[b * NSEQ + cj]; break;
      default: hb = El; r = (size_t)b * NSEQ + idx1[b * NSEQ + cj]; break;
    }
    src = hb + r * NDIM;
  }
  char* dst = stage + tile * (32 * LROW) + srow * LROW;
  char* Qh_ = stage;
  char* Ql_ = stage + 1 * (32 * LROW);
  char* Kh_ = stage + 2 * (32 * LROW);
  char* Kl_ = stage + 3 * (32 * LROW);
  char* Eh_ = stage + 4 * (32 * LROW);
  char* El_ = stage + 5 * (32 * LROW);
  char* Fh_ = stage + 6 * (32 * LROW);
  char* Fl_ = stage + 7 * (32 * LROW);

  f32x4 accL = (f32x4){0.f, 0.f, 0.f, 0.f};
  f32x4 accS = (f32x4){0.f, 0.f, 0.f, 0.f};
  int qrow = ih * 16 + fr, krow = jh * 16 + fr;

  // prologue: load K-step 0
  uint4 v0 = *(const uint4*)(src);
  uint4 v1 = *(const uint4*)(src + 8);
  uint4 v2 = *(const uint4*)(src + 16);
  uint4 v3 = *(const uint4*)(src + 24);

  for (int k0 = 0; k0 < NDIM; k0 += 32){
    __syncthreads();
    *(uint4*)(dst)      = v0;
    *(uint4*)(dst + 16) = v1;
    *(uint4*)(dst + 32) = v2;
    *(uint4*)(dst + 48) = v3;
    __syncthreads();

    // prefetch next K-step before MFMA
    int kn = k0 + 32;
    if (kn < NDIM){
      v0 = *(const uint4*)(src + kn);
      v1 = *(const uint4*)(src + kn + 8);
      v2 = *(const uint4*)(src + kn + 16);
      v3 = *(const uint4*)(src + kn + 24);
    }

    bf16x8 qh = *(const bf16x8*)(Qh_ + qrow * LROW + kg * 16);
    bf16x8 ql = *(const bf16x8*)(Ql_ + qrow * LROW + kg * 16);
    bf16x8 kh = *(const bf16x8*)(Kh_ + krow * LROW + kg * 16);
    bf16x8 kl = *(const bf16x8*)(Kl_ + krow * LROW + kg * 16);
    bf16x8 eh = *(const bf16x8*)(Eh_ + qrow * LROW + kg * 16);
    bf16x8 el = *(const bf16x8*)(El_ + qrow * LROW + kg * 16);
    bf16x8 fh = *(const bf16x8*)(Fh_ + krow * LROW + kg * 16);
    bf16x8 fl = *(const bf16x8*)(Fl_ + krow * LROW + kg * 16);

    accL = __builtin_amdgcn_mfma_f32_16x16x32_bf16(qh, kh, accL, 0, 0, 0);
    accL = __builtin_amdgcn_mfma_f32_16x16x32_bf16(qh, kl, accL, 0, 0, 0);
    accL = __builtin_amdgcn_mfma_f32_16x16x32_bf16(ql, kh, accL, 0, 0, 0);
    accS = __builtin_amdgcn_mfma_f32_16x16x32_bf16(eh, fh, accS, 0, 0, 0);
    accS = __builtin_amdgcn_mfma_f32_16x16x32_bf16(eh, fl, accS, 0, 0, 0);
    accS = __builtin_amdgcn_mfma_f32_16x16x32_bf16(el, fh, accS, 0, 0, 0);
  }

  __syncthreads();
  #pragma unroll
  for (int reg = 0; reg < 4; ++reg){
    int li = ih * 16 + (kg << 2) + reg, lj = jh * 16 + fr;
    Lout[li * 32 + lj] = accL[reg];
    Sout[li * 32 + lj] = accS[reg];
  }
  __syncthreads();

  // block-wide flattened softmax partials over the 32x32 tile
  float m = NEGBIG, dsum = 0.f, nsum = 0.f;
  #pragma unroll
  for (int u = 0; u < 4; ++u){
    int l = t + (u << 8);
    int i = l >> 5, j = l & 31;
    if ((ibase + i < nn0) && (jbase + j < nn1)){
      float L = Lout[l];
      float S = Sout[l];
      float rnI = rnorm[b * NSEQ + idx0[b * NSEQ + ibase + i]];
      float rnJ = rnorm[b * NSEQ + idx1[b * NSEQ + jbase + j]];
      float mm = fmaxf(m, L);
      float wold = expf(m - mm);
      float e = expf(L - mm);
      dsum = dsum * wold + e;
      nsum = nsum * wold + e * fabsf(S) * rnI * rnJ;
      m = mm;
    }
  }
  #pragma unroll
  for (int off = 1; off < 64; off <<= 1){
    float m2 = __shfl_xor(m, off, 64);
    float d2 = __shfl_xor(dsum, off, 64);
    float s2 = __shfl_xor(nsum, off, 64);
    float mm = fmaxf(m, m2);
    float w1 = expf(m - mm), w2 = expf(m2 - mm);
    dsum = dsum * w1 + d2 * w2;
    nsum = nsum * w1 + s2 * w2;
    m = mm;
  }
  if (lane == 0){ red[w * 3 + 0] = m; red[w * 3 + 1] = dsum; red[w * 3 + 2] = nsum; }
  __syncthreads();
  if (t == 0){
    float M = NEGBIG, D = 0.f, N = 0.f;
    #pragma unroll
    for (int ww = 0; ww < 4; ++ww){
      float m2 = red[ww * 3 + 0], d2 = red[ww * 3 + 1], n2 = red[ww * 3 + 2];
      float mm = fmaxf(M, m2);
      float w1 = expf(M - mm), w2 = expf(m2 - mm);
      D = D * w1 + d2 * w2;
      N = N * w1 + n2 * w2;
      M = mm;
    }
    float* pp = partials + ((size_t)b * 256 + (blockIdx.x << 4) + blockIdx.y) * 3;
    pp[0] = M; pp[1] = D; pp[2] = N;
  }
}

// ---------------- finalize: merge tile partials per batch ----------------
__global__ __launch_bounds__(64)
void k_final(const float* __restrict__ partials, const int* __restrict__ n0a,
             const int* __restrict__ n1a, float* __restrict__ out){
  int b = blockIdx.x, lane = threadIdx.x;
  int nn0 = n0a[b], nn1 = n1a[b];
  float m = NEGBIG, d = 0.f, n = 0.f;
  if (nn0 > 0 && nn1 > 0){
    int nti = (nn0 + 31) >> 5, ntj = (nn1 + 31) >> 5;
    int cnt = nti * ntj;
    for (int s = lane; s < cnt; s += 64){
      int it = s / ntj, jt = s - it * ntj;
      const float* pp = partials + ((size_t)b * 256 + (it << 4) + jt) * 3;
      float m2 = pp[0], d2 = pp[1], n2 = pp[2];
      float mm = fmaxf(m, m2);
      float w1 = expf(m - mm), w2 = expf(m2 - mm);
      d = d * w1 + d2 * w2;
      n = n * w1 + n2 * w2;
      m = mm;
    }
  }
  #pragma unroll
  for (int off = 1; off < 64; off <<= 1){
    float m2 = __shfl_xor(m, off, 64);
    float d2 = __shfl_xor(d, off, 64);
    float n2 = __shfl_xor(n, off, 64);
    float mm = fmaxf(m, m2);
    float w1 = expf(m - mm), w2 = expf(m2 - mm);
    d = d * w1 + d2 * w2;
    n = n * w1 + n2 * w2;
    m = mm;
  }
  if (lane == 0) out[b] = (d > 0.f) ? (n / d) : 0.f;
}

extern "C" void kernel_launch(void* const* d_in, const int* in_sizes, int n_in,
                              void* d_out, int out_size, void* d_ws, size_t ws_size,
                              hipStream_t stream) {
  const float* emb = (const float*)d_in[0];
  const float* Wq  = (const float*)d_in[1];
  const float* bq  = (const float*)d_in[2];
  const float* Wk  = (const float*)d_in[3];
  const float* bk  = (const float*)d_in[4];
  const int*   am  = (const int*)d_in[5];
  const int*   tt  = (const int*)d_in[6];
  float* out = (float*)d_out;

  // workspace layout (~72.2 MB)
  char* ws = (char*)d_ws;
  unsigned short* Eh  = (unsigned short*)(ws);                        // 16 MB
  unsigned short* El  = (unsigned short*)(ws + (1u << 24));           // 16 MB
  unsigned short* Ph  = (unsigned short*)(ws + 2u * (1u << 24));      // 16 MB
  unsigned short* Pl  = (unsigned short*)(ws + 3u * (1u << 24));      // 16 MB
  unsigned short* Wqh = (unsigned short*)(ws + 4u * (1u << 24));      // 2 MB
  unsigned short* Wql = (unsigned short*)(ws + 4u * (1u << 24) + 1u * (1u << 21));
  unsigned short* Wkh = (unsigned short*)(ws + 4u * (1u << 24) + 2u * (1u << 21));
  unsigned short* Wkl = (unsigned short*)(ws + 4u * (1u << 24) + 3u * (1u << 21));
  char* misc = ws + 4u * (1u << 24) + 4u * (1u << 21);
  int*   idx0  = (int*)misc;
  int*   idx1  = idx0 + NBATCH * NSEQ;
  int*   n0    = idx1 + NBATCH * NSEQ;
  int*   n1    = n0 + NBATCH;
  float* rnorm = (float*)(n1 + NBATCH);
  float* partials = rnorm + NBATCH * NSEQ;

  k_compact<<<dim3(NBATCH), dim3(NSEQ), 0, stream>>>(am, tt, idx0, idx1, n0, n1);
  k_rnorm<<<dim3(NBATCH * NSEQ / 4), dim3(256), 0, stream>>>(emb, rnorm);
  k_conv<<<dim3(4096), dim3(256), 0, stream>>>(emb, Eh, El, NBATCH * NSEQ * NDIM / 8);
  k_conv<<<dim3(512), dim3(256), 0, stream>>>(Wq, Wqh, Wql, NDIM * NDIM / 8);
  k_conv<<<dim3(512), dim3(256), 0, stream>>>(Wk, Wkh, Wkl, NDIM * NDIM / 8);
  k_proj<<<dim3(8, 8, NBATCH * 2), dim3(256), 0, stream>>>(Eh, El, Wqh, Wql, Wkh, Wkl,
                                                           bq, bk, idx0, idx1, n0, n1, Ph, Pl);
  k_pair<<<dim3(16, 16, NBATCH), dim3(256), 0, stream>>>(Ph, Pl, Eh, El, idx0, idx1,
                                                         n0, n1, rnorm, partials);
  k_final<<<dim3(NBATCH), dim3(64), 0, stream>>>(partials, n0, n1, out);
}

// Round 11
// 263.345 us; speedup vs baseline: 19.2174x; 1.2301x over previous
//
#include <hip/hip_runtime.h>
#include <math.h>

#define NBATCH 16
#define NSEQ   512
#define NDIM   1024
#define NEGBIG (-1e30f)

typedef __attribute__((ext_vector_type(8))) short bf16x8;
typedef __attribute__((ext_vector_type(8))) unsigned short u16x8;
typedef __attribute__((ext_vector_type(4))) float f32x4;

// LDS row stride for 32-bf16 (64B) tile rows: 80B (odd multiple of 16B).
#define LROW 80

// f32 -> bf16 hi (truncate) + bf16 lo (exact residual, truncated).
__device__ __forceinline__ void split1(float f, unsigned short& h, unsigned short& l){
  unsigned u = __float_as_uint(f);
  h = (unsigned short)(u >> 16);
  float fl = f - __uint_as_float(u & 0xffff0000u);
  l = (unsigned short)(__float_as_uint(fl) >> 16);
}

// ---------------- mask compaction ----------------
__global__ __launch_bounds__(512)
void k_compact(const int* __restrict__ am, const int* __restrict__ tt,
               int* __restrict__ idx0, int* __restrict__ idx1,
               int* __restrict__ n0, int* __restrict__ n1){
  int b = blockIdx.x, t = threadIdx.x;
  int a = am[b * NSEQ + t];
  int y = tt[b * NSEQ + t];
  bool p0 = (a == 1) && (y == 0);
  bool p1 = (a == 1) && (y == 1);
  __shared__ int wc0[8], wc1[8], wo0[8], wo1[8];
  int wave = t >> 6, lane = t & 63;
  unsigned long long m0 = __ballot(p0);
  unsigned long long m1 = __ballot(p1);
  unsigned long long below = (1ULL << lane) - 1ULL;
  int r0 = __popcll(m0 & below);
  int r1 = __popcll(m1 & below);
  if (lane == 0){ wc0[wave] = __popcll(m0); wc1[wave] = __popcll(m1); }
  __syncthreads();
  if (t == 0){
    int s0 = 0, s1 = 0;
    for (int w = 0; w < 8; ++w){ wo0[w] = s0; s0 += wc0[w]; wo1[w] = s1; s1 += wc1[w]; }
    n0[b] = s0; n1[b] = s1;
  }
  __syncthreads();
  if (p0) idx0[b * NSEQ + wo0[wave] + r0] = t;
  if (p1) idx1[b * NSEQ + wo1[wave] + r1] = t;
}

// ---------------- per-row 1/max(||x||,eps) ----------------
__global__ __launch_bounds__(256)
void k_rnorm(const float* __restrict__ emb, float* __restrict__ rnorm){
  int wave = threadIdx.x >> 6, lane = threadIdx.x & 63;
  int row = blockIdx.x * 4 + wave;
  const float4* p = (const float4*)(emb + (size_t)row * NDIM);
  float ss = 0.f;
  #pragma unroll
  for (int i = 0; i < 4; ++i){
    float4 v = p[i * 64 + lane];
    ss += v.x*v.x + v.y*v.y + v.z*v.z + v.w*v.w;
  }
  #pragma unroll
  for (int off = 32; off > 0; off >>= 1) ss += __shfl_down(ss, off, 64);
  if (lane == 0) rnorm[row] = 1.f / fmaxf(sqrtf(ss), 1e-12f);
}

// ---------------- f32 -> bf16 hi/lo pre-conversion ----------------
__global__ __launch_bounds__(256)
void k_conv(const float* __restrict__ src, unsigned short* __restrict__ hi,
            unsigned short* __restrict__ lo, int n8){
  int t = blockIdx.x * 256 + threadIdx.x;
  if (t >= n8) return;
  const float4* s = (const float4*)(src + (size_t)t * 8);
  float4 a = s[0], b = s[1];
  float v[8] = {a.x, a.y, a.z, a.w, b.x, b.y, b.z, b.w};
  u16x8 h, l;
  #pragma unroll
  for (int i = 0; i < 8; ++i){
    unsigned short hh, ll; split1(v[i], hh, ll); h[i] = hh; l[i] = ll;
  }
  *(u16x8*)(hi + (size_t)t * 8) = h;
  *(u16x8*)(lo + (size_t)t * 8) = l;
}

// ---------------- MFMA projection GEMM (bf16 3-pass hi/lo split) ----------
// GRID: x = col-tile (ALWAYS active -> linear ids cover all XCD residues),
// y = row-tile (early-exits), z = b*2+which. 256 threads / 4 waves.
__global__ __launch_bounds__(256)
void k_proj(const unsigned short* __restrict__ Eh, const unsigned short* __restrict__ El,
            const unsigned short* __restrict__ Wqh, const unsigned short* __restrict__ Wql,
            const unsigned short* __restrict__ Wkh, const unsigned short* __restrict__ Wkl,
            const float* __restrict__ bq, const float* __restrict__ bk,
            const int* __restrict__ idx0, const int* __restrict__ idx1,
            const int* __restrict__ n0, const int* __restrict__ n1,
            unsigned short* __restrict__ Ph, unsigned short* __restrict__ Pl){
  int z = blockIdx.z;
  int b = z >> 1, which = z & 1;
  int cnt = which ? n1[b] : n0[b];
  int rbase = blockIdx.y << 6;          // early-exit dim moved to y
  if (cnt == 0 || rbase >= cnt) return;
  const unsigned short* __restrict__ Wh = which ? Wkh : Wqh;
  const unsigned short* __restrict__ Wl = which ? Wkl : Wql;
  const float* __restrict__ bias = which ? bk : bq;
  const int*   __restrict__ idx  = (which ? idx1 : idx0) + b * NSEQ;
  int dstOff = which ? n0[b] : 0;
  int cbase = blockIdx.x << 7;          // always-active dim is x

  __shared__ __align__(16) char Ah[64 * LROW], Al[64 * LROW];
  __shared__ __align__(16) char Bh[128 * LROW], Bl[128 * LROW];

  int t = threadIdx.x;
  int w = t >> 6, lane = t & 63;
  int wm = w >> 1, wn = w & 1;
  int fr = lane & 15, kg = lane >> 4;

  int srow = t >> 2, schk = t & 3;
  int ar = min(rbase + srow, cnt - 1);
  size_t aoff = ((size_t)b * NSEQ + idx[ar]) * NDIM + schk * 8;
  const unsigned short* aSh = Eh + aoff;
  const unsigned short* aSl = El + aoff;
  const unsigned short* bSh0 = Wh + (size_t)(cbase + srow) * NDIM + schk * 8;
  const unsigned short* bSl0 = Wl + (size_t)(cbase + srow) * NDIM + schk * 8;
  const unsigned short* bSh1 = Wh + (size_t)(cbase + srow + 64) * NDIM + schk * 8;
  const unsigned short* bSl1 = Wl + (size_t)(cbase + srow + 64) * NDIM + schk * 8;
  char* aDh = Ah + srow * LROW + schk * 16;
  char* aDl = Al + srow * LROW + schk * 16;
  char* bDh0 = Bh + srow * LROW + schk * 16;
  char* bDl0 = Bl + srow * LROW + schk * 16;
  char* bDh1 = Bh + (srow + 64) * LROW + schk * 16;
  char* bDl1 = Bl + (srow + 64) * LROW + schk * 16;

  f32x4 acc[2][4];
  #pragma unroll
  for (int i = 0; i < 2; ++i)
    #pragma unroll
    for (int j = 0; j < 4; ++j) acc[i][j] = (f32x4){0.f, 0.f, 0.f, 0.f};

  uint4 v0 = *(const uint4*)(aSh);
  uint4 v1 = *(const uint4*)(aSl);
  uint4 v2 = *(const uint4*)(bSh0);
  uint4 v3 = *(const uint4*)(bSl0);
  uint4 v4 = *(const uint4*)(bSh1);
  uint4 v5 = *(const uint4*)(bSl1);

  for (int k0 = 0; k0 < NDIM; k0 += 32){
    __syncthreads();
    *(uint4*)aDh = v0;  *(uint4*)aDl = v1;
    *(uint4*)bDh0 = v2; *(uint4*)bDl0 = v3;
    *(uint4*)bDh1 = v4; *(uint4*)bDl1 = v5;
    __syncthreads();

    int kn = k0 + 32;
    if (kn < NDIM){
      v0 = *(const uint4*)(aSh + kn);
      v1 = *(const uint4*)(aSl + kn);
      v2 = *(const uint4*)(bSh0 + kn);
      v3 = *(const uint4*)(bSl0 + kn);
      v4 = *(const uint4*)(bSh1 + kn);
      v5 = *(const uint4*)(bSl1 + kn);
    }

    bf16x8 ah[2], al_[2], bh[4], bl_[4];
    #pragma unroll
    for (int fm = 0; fm < 2; ++fm){
      int r = wm * 32 + fm * 16 + fr;
      ah[fm]  = *(const bf16x8*)(Ah + r * LROW + kg * 16);
      al_[fm] = *(const bf16x8*)(Al + r * LROW + kg * 16);
    }
    #pragma unroll
    for (int fn = 0; fn < 4; ++fn){
      int r = wn * 64 + fn * 16 + fr;
      bh[fn]  = *(const bf16x8*)(Bh + r * LROW + kg * 16);
      bl_[fn] = *(const bf16x8*)(Bl + r * LROW + kg * 16);
    }
    #pragma unroll
    for (int fm = 0; fm < 2; ++fm)
      #pragma unroll
      for (int fn = 0; fn < 4; ++fn){
        acc[fm][fn] = __builtin_amdgcn_mfma_f32_16x16x32_bf16(ah[fm], bh[fn], acc[fm][fn], 0, 0, 0);
        acc[fm][fn] = __builtin_amdgcn_mfma_f32_16x16x32_bf16(ah[fm], bl_[fn], acc[fm][fn], 0, 0, 0);
        acc[fm][fn] = __builtin_amdgcn_mfma_f32_16x16x32_bf16(al_[fm], bh[fn], acc[fm][fn], 0, 0, 0);
      }
  }

  // C/D layout (m89-verified): col = lane&15, row = (lane>>4)*4 + reg
  #pragma unroll
  for (int fm = 0; fm < 2; ++fm)
    #pragma unroll
    for (int fn = 0; fn < 4; ++fn)
      #pragma unroll
      for (int reg = 0; reg < 4; ++reg){
        int rloc = wm * 32 + fm * 16 + (kg << 2) + reg;
        if (rbase + rloc < cnt){
          int gc = cbase + wn * 64 + fn * 16 + fr;
          float v = acc[fm][fn][reg] + bias[gc];
          unsigned short h, l; split1(v, h, l);
          size_t o = ((size_t)b * NSEQ + dstOff + rbase + rloc) * NDIM + gc;
          Ph[o] = h; Pl[o] = l;
        }
      }
}

// ---------------- pair phase: MFMA logits + |cos| + tile softmax partials --
// GRID: x = batch (ALWAYS active -> XCD spread), y = i-tile, z = j-tile.
__global__ __launch_bounds__(256)
void k_pair(const unsigned short* __restrict__ Ph, const unsigned short* __restrict__ Pl,
            const unsigned short* __restrict__ Eh, const unsigned short* __restrict__ El,
            const int* __restrict__ idx0, const int* __restrict__ idx1,
            const int* __restrict__ n0a, const int* __restrict__ n1a,
            const float* __restrict__ rnorm, float* __restrict__ partials){
  int b = blockIdx.x;
  int nn0 = n0a[b], nn1 = n1a[b];
  int ibase = blockIdx.y << 5, jbase = blockIdx.z << 5;
  if (nn0 == 0 || nn1 == 0 || ibase >= nn0 || jbase >= nn1) return;

  __shared__ __align__(16) char stage[8 * 32 * LROW];  // Qh Ql Kh Kl Eh El Fh Fl
  __shared__ __align__(16) float Lout[1024];
  __shared__ __align__(16) float Sout[1024];
  __shared__ float red[12];

  int t = threadIdx.x;
  int w = t >> 6, lane = t & 63;
  int ih = w >> 1, jh = w & 1;
  int fr = lane & 15, kg = lane >> 4;

  int tile = t >> 5, srow = t & 31;
  const unsigned short* src;
  {
    int ci = min(ibase + srow, nn0 - 1);
    int cj = min(jbase + srow, nn1 - 1);
    const unsigned short* hb; size_t r;
    switch (tile){
      case 0: hb = Ph; r = (size_t)b * NSEQ + ci; break;
      case 1: hb = Pl; r = (size_t)b * NSEQ + ci; break;
      case 2: hb = Ph; r = (size_t)b * NSEQ + nn0 + cj; break;
      case 3: hb = Pl; r = (size_t)b * NSEQ + nn0 + cj; break;
      case 4: hb = Eh; r = (size_t)b * NSEQ + idx0[b * NSEQ + ci]; break;
      case 5: hb = El; r = (size_t)b * NSEQ + idx0[b * NSEQ + ci]; break;
      case 6: hb = Eh; r = (size_t)b * NSEQ + idx1[b * NSEQ + cj]; break;
      default: hb = El; r = (size_t)b * NSEQ + idx1[b * NSEQ + cj]; break;
    }
    src = hb + r * NDIM;
  }
  char* dst = stage + tile * (32 * LROW) + srow * LROW;
  char* Qh_ = stage;
  char* Ql_ = stage + 1 * (32 * LROW);
  char* Kh_ = stage + 2 * (32 * LROW);
  char* Kl_ = stage + 3 * (32 * LROW);
  char* Eh_ = stage + 4 * (32 * LROW);
  char* El_ = stage + 5 * (32 * LROW);
  char* Fh_ = stage + 6 * (32 * LROW);
  char* Fl_ = stage + 7 * (32 * LROW);

  f32x4 accL = (f32x4){0.f, 0.f, 0.f, 0.f};
  f32x4 accS = (f32x4){0.f, 0.f, 0.f, 0.f};
  int qrow = ih * 16 + fr, krow = jh * 16 + fr;

  uint4 v0 = *(const uint4*)(src);
  uint4 v1 = *(const uint4*)(src + 8);
  uint4 v2 = *(const uint4*)(src + 16);
  uint4 v3 = *(const uint4*)(src + 24);

  for (int k0 = 0; k0 < NDIM; k0 += 32){
    __syncthreads();
    *(uint4*)(dst)      = v0;
    *(uint4*)(dst + 16) = v1;
    *(uint4*)(dst + 32) = v2;
    *(uint4*)(dst + 48) = v3;
    __syncthreads();

    int kn = k0 + 32;
    if (kn < NDIM){
      v0 = *(const uint4*)(src + kn);
      v1 = *(const uint4*)(src + kn + 8);
      v2 = *(const uint4*)(src + kn + 16);
      v3 = *(const uint4*)(src + kn + 24);
    }

    bf16x8 qh = *(const bf16x8*)(Qh_ + qrow * LROW + kg * 16);
    bf16x8 ql = *(const bf16x8*)(Ql_ + qrow * LROW + kg * 16);
    bf16x8 kh = *(const bf16x8*)(Kh_ + krow * LROW + kg * 16);
    bf16x8 kl = *(const bf16x8*)(Kl_ + krow * LROW + kg * 16);
    bf16x8 eh = *(const bf16x8*)(Eh_ + qrow * LROW + kg * 16);
    bf16x8 el = *(const bf16x8*)(El_ + qrow * LROW + kg * 16);
    bf16x8 fh = *(const bf16x8*)(Fh_ + krow * LROW + kg * 16);
    bf16x8 fl = *(const bf16x8*)(Fl_ + krow * LROW + kg * 16);

    accL = __builtin_amdgcn_mfma_f32_16x16x32_bf16(qh, kh, accL, 0, 0, 0);
    accL = __builtin_amdgcn_mfma_f32_16x16x32_bf16(qh, kl, accL, 0, 0, 0);
    accL = __builtin_amdgcn_mfma_f32_16x16x32_bf16(ql, kh, accL, 0, 0, 0);
    accS = __builtin_amdgcn_mfma_f32_16x16x32_bf16(eh, fh, accS, 0, 0, 0);
    accS = __builtin_amdgcn_mfma_f32_16x16x32_bf16(eh, fl, accS, 0, 0, 0);
    accS = __builtin_amdgcn_mfma_f32_16x16x32_bf16(el, fh, accS, 0, 0, 0);
  }

  __syncthreads();
  #pragma unroll
  for (int reg = 0; reg < 4; ++reg){
    int li = ih * 16 + (kg << 2) + reg, lj = jh * 16 + fr;
    Lout[li * 32 + lj] = accL[reg];
    Sout[li * 32 + lj] = accS[reg];
  }
  __syncthreads();

  float m = NEGBIG, dsum = 0.f, nsum = 0.f;
  #pragma unroll
  for (int u = 0; u < 4; ++u){
    int l = t + (u << 8);
    int i = l >> 5, j = l & 31;
    if ((ibase + i < nn0) && (jbase + j < nn1)){
      float L = Lout[l];
      float S = Sout[l];
      float rnI = rnorm[b * NSEQ + idx0[b * NSEQ + ibase + i]];
      float rnJ = rnorm[b * NSEQ + idx1[b * NSEQ + jbase + j]];
      float mm = fmaxf(m, L);
      float wold = expf(m - mm);
      float e = expf(L - mm);
      dsum = dsum * wold + e;
      nsum = nsum * wold + e * fabsf(S) * rnI * rnJ;
      m = mm;
    }
  }
  #pragma unroll
  for (int off = 1; off < 64; off <<= 1){
    float m2 = __shfl_xor(m, off, 64);
    float d2 = __shfl_xor(dsum, off, 64);
    float s2 = __shfl_xor(nsum, off, 64);
    float mm = fmaxf(m, m2);
    float w1 = expf(m - mm), w2 = expf(m2 - mm);
    dsum = dsum * w1 + d2 * w2;
    nsum = nsum * w1 + s2 * w2;
    m = mm;
  }
  if (lane == 0){ red[w * 3 + 0] = m; red[w * 3 + 1] = dsum; red[w * 3 + 2] = nsum; }
  __syncthreads();
  if (t == 0){
    float M = NEGBIG, D = 0.f, N = 0.f;
    #pragma unroll
    for (int ww = 0; ww < 4; ++ww){
      float m2 = red[ww * 3 + 0], d2 = red[ww * 3 + 1], n2 = red[ww * 3 + 2];
      float mm = fmaxf(M, m2);
      float w1 = expf(M - mm), w2 = expf(m2 - mm);
      D = D * w1 + d2 * w2;
      N = N * w1 + n2 * w2;
      M = mm;
    }
    float* pp = partials + ((size_t)b * 256 + (blockIdx.y << 4) + blockIdx.z) * 3;
    pp[0] = M; pp[1] = D; pp[2] = N;
  }
}

// ---------------- finalize: merge tile partials per batch ----------------
__global__ __launch_bounds__(64)
void k_final(const float* __restrict__ partials, const int* __restrict__ n0a,
             const int* __restrict__ n1a, float* __restrict__ out){
  int b = blockIdx.x, lane = threadIdx.x;
  int nn0 = n0a[b], nn1 = n1a[b];
  float m = NEGBIG, d = 0.f, n = 0.f;
  if (nn0 > 0 && nn1 > 0){
    int nti = (nn0 + 31) >> 5, ntj = (nn1 + 31) >> 5;
    int cnt = nti * ntj;
    for (int s = lane; s < cnt; s += 64){
      int it = s / ntj, jt = s - it * ntj;
      const float* pp = partials + ((size_t)b * 256 + (it << 4) + jt) * 3;
      float m2 = pp[0], d2 = pp[1], n2 = pp[2];
      float mm = fmaxf(m, m2);
      float w1 = expf(m - mm), w2 = expf(m2 - mm);
      d = d * w1 + d2 * w2;
      n = n * w1 + n2 * w2;
      m = mm;
    }
  }
  #pragma unroll
  for (int off = 1; off < 64; off <<= 1){
    float m2 = __shfl_xor(m, off, 64);
    float d2 = __shfl_xor(d, off, 64);
    float n2 = __shfl_xor(n, off, 64);
    float mm = fmaxf(m, m2);
    float w1 = expf(m - mm), w2 = expf(m2 - mm);
    d = d * w1 + d2 * w2;
    n = n * w1 + n2 * w2;
    m = mm;
  }
  if (lane == 0) out[b] = (d > 0.f) ? (n / d) : 0.f;
}

extern "C" void kernel_launch(void* const* d_in, const int* in_sizes, int n_in,
                              void* d_out, int out_size, void* d_ws, size_t ws_size,
                              hipStream_t stream) {
  const float* emb = (const float*)d_in[0];
  const float* Wq  = (const float*)d_in[1];
  const float* bq  = (const float*)d_in[2];
  const float* Wk  = (const float*)d_in[3];
  const float* bk  = (const float*)d_in[4];
  const int*   am  = (const int*)d_in[5];
  const int*   tt  = (const int*)d_in[6];
  float* out = (float*)d_out;

  // workspace layout (~72.2 MB)
  char* ws = (char*)d_ws;
  unsigned short* Eh  = (unsigned short*)(ws);                        // 16 MB
  unsigned short* El  = (unsigned short*)(ws + (1u << 24));           // 16 MB
  unsigned short* Ph  = (unsigned short*)(ws + 2u * (1u << 24));      // 16 MB
  unsigned short* Pl  = (unsigned short*)(ws + 3u * (1u << 24));      // 16 MB
  unsigned short* Wqh = (unsigned short*)(ws + 4u * (1u << 24));      // 2 MB
  unsigned short* Wql = (unsigned short*)(ws + 4u * (1u << 24) + 1u * (1u << 21));
  unsigned short* Wkh = (unsigned short*)(ws + 4u * (1u << 24) + 2u * (1u << 21));
  unsigned short* Wkl = (unsigned short*)(ws + 4u * (1u << 24) + 3u * (1u << 21));
  char* misc = ws + 4u * (1u << 24) + 4u * (1u << 21);
  int*   idx0  = (int*)misc;
  int*   idx1  = idx0 + NBATCH * NSEQ;
  int*   n0    = idx1 + NBATCH * NSEQ;
  int*   n1    = n0 + NBATCH;
  float* rnorm = (float*)(n1 + NBATCH);
  float* partials = rnorm + NBATCH * NSEQ;

  k_compact<<<dim3(NBATCH), dim3(NSEQ), 0, stream>>>(am, tt, idx0, idx1, n0, n1);
  k_rnorm<<<dim3(NBATCH * NSEQ / 4), dim3(256), 0, stream>>>(emb, rnorm);
  k_conv<<<dim3(4096), dim3(256), 0, stream>>>(emb, Eh, El, NBATCH * NSEQ * NDIM / 8);
  k_conv<<<dim3(512), dim3(256), 0, stream>>>(Wq, Wqh, Wql, NDIM * NDIM / 8);
  k_conv<<<dim3(512), dim3(256), 0, stream>>>(Wk, Wkh, Wkl, NDIM * NDIM / 8);
  // x = always-active dim (XCD spread); y = early-exit row-tile dim
  k_proj<<<dim3(8, 8, NBATCH * 2), dim3(256), 0, stream>>>(Eh, El, Wqh, Wql, Wkh, Wkl,
                                                           bq, bk, idx0, idx1, n0, n1, Ph, Pl);
  k_pair<<<dim3(NBATCH, 16, 16), dim3(256), 0, stream>>>(Ph, Pl, Eh, El, idx0, idx1,
                                                         n0, n1, rnorm, partials);
  k_final<<<dim3(NBATCH), dim3(64), 0, stream>>>(partials, n0, n1, out);
}

// Round 12
// 232.447 us; speedup vs baseline: 21.7719x; 1.1329x over previous
//
#include <hip/hip_runtime.h>
#include <math.h>

#define NBATCH 16
#define NSEQ   512
#define NDIM   1024
#define NEGBIG (-1e30f)

typedef __attribute__((ext_vector_type(8))) short bf16x8;
typedef __attribute__((ext_vector_type(8))) unsigned short u16x8;
typedef __attribute__((ext_vector_type(4))) float f32x4;

// LDS row stride for 32-bf16 (64B) tile rows: 80B (odd multiple of 16B).
#define LROW 80

// f32 -> bf16 hi (truncate) + bf16 lo (exact residual, truncated).
__device__ __forceinline__ void split1(float f, unsigned short& h, unsigned short& l){
  unsigned u = __float_as_uint(f);
  h = (unsigned short)(u >> 16);
  float fl = f - __uint_as_float(u & 0xffff0000u);
  l = (unsigned short)(__float_as_uint(fl) >> 16);
}

// ---------------- mask compaction ----------------
__global__ __launch_bounds__(512)
void k_compact(const int* __restrict__ am, const int* __restrict__ tt,
               int* __restrict__ idx0, int* __restrict__ idx1,
               int* __restrict__ n0, int* __restrict__ n1){
  int b = blockIdx.x, t = threadIdx.x;
  int a = am[b * NSEQ + t];
  int y = tt[b * NSEQ + t];
  bool p0 = (a == 1) && (y == 0);
  bool p1 = (a == 1) && (y == 1);
  __shared__ int wc0[8], wc1[8], wo0[8], wo1[8];
  int wave = t >> 6, lane = t & 63;
  unsigned long long m0 = __ballot(p0);
  unsigned long long m1 = __ballot(p1);
  unsigned long long below = (1ULL << lane) - 1ULL;
  int r0 = __popcll(m0 & below);
  int r1 = __popcll(m1 & below);
  if (lane == 0){ wc0[wave] = __popcll(m0); wc1[wave] = __popcll(m1); }
  __syncthreads();
  if (t == 0){
    int s0 = 0, s1 = 0;
    for (int w = 0; w < 8; ++w){ wo0[w] = s0; s0 += wc0[w]; wo1[w] = s1; s1 += wc1[w]; }
    n0[b] = s0; n1[b] = s1;
  }
  __syncthreads();
  if (p0) idx0[b * NSEQ + wo0[wave] + r0] = t;
  if (p1) idx1[b * NSEQ + wo1[wave] + r1] = t;
}

// ---------------- fused: gather compacted rows, rnorm + bf16 hi/lo split ---
// One wave per compacted row (s0 rows at [0,n0), s1 rows at [n0,n0+n1) —
// same layout as P). Replaces k_rnorm + full-emb k_conv (128 MB -> 32 MB).
__global__ __launch_bounds__(256)
void k_conv2(const float* __restrict__ emb, const int* __restrict__ idx0,
             const int* __restrict__ idx1, const int* __restrict__ n0,
             const int* __restrict__ n1, unsigned short* __restrict__ Ehc,
             unsigned short* __restrict__ Elc, float* __restrict__ rnormc){
  int b = blockIdx.x;
  int wave = threadIdx.x >> 6, lane = threadIdx.x & 63;
  int pos = blockIdx.y * 4 + wave;
  int nn0 = n0[b], nn1 = n1[b];
  if (pos >= nn0 + nn1) return;
  int srcRow = (pos < nn0) ? idx0[b * NSEQ + pos] : idx1[b * NSEQ + pos - nn0];
  const float4* src = (const float4*)(emb + ((size_t)b * NSEQ + srcRow) * NDIM);
  float4 v[4];
  float ss = 0.f;
  #pragma unroll
  for (int i = 0; i < 4; ++i){
    v[i] = src[i * 64 + lane];
    ss += v[i].x*v[i].x + v[i].y*v[i].y + v[i].z*v[i].z + v[i].w*v[i].w;
  }
  #pragma unroll
  for (int off = 32; off > 0; off >>= 1) ss += __shfl_down(ss, off, 64);
  if (lane == 0) rnormc[b * NSEQ + pos] = 1.f / fmaxf(sqrtf(ss), 1e-12f);
  size_t dst = ((size_t)b * NSEQ + pos) * NDIM;
  #pragma unroll
  for (int i = 0; i < 4; ++i){
    ushort4 h, l;
    split1(v[i].x, h.x, l.x); split1(v[i].y, h.y, l.y);
    split1(v[i].z, h.z, l.z); split1(v[i].w, h.w, l.w);
    *(ushort4*)(Ehc + dst + (size_t)(i * 64 + lane) * 4) = h;
    *(ushort4*)(Elc + dst + (size_t)(i * 64 + lane) * 4) = l;
  }
}

// ---------------- f32 -> bf16 hi/lo pre-conversion (weights) ----------------
__global__ __launch_bounds__(256)
void k_conv(const float* __restrict__ src, unsigned short* __restrict__ hi,
            unsigned short* __restrict__ lo, int n8){
  int t = blockIdx.x * 256 + threadIdx.x;
  if (t >= n8) return;
  const float4* s = (const float4*)(src + (size_t)t * 8);
  float4 a = s[0], b = s[1];
  float v[8] = {a.x, a.y, a.z, a.w, b.x, b.y, b.z, b.w};
  u16x8 h, l;
  #pragma unroll
  for (int i = 0; i < 8; ++i){
    unsigned short hh, ll; split1(v[i], hh, ll); h[i] = hh; l[i] = ll;
  }
  *(u16x8*)(hi + (size_t)t * 8) = h;
  *(u16x8*)(lo + (size_t)t * 8) = l;
}

// ---------------- MFMA projection GEMM (bf16 3-pass hi/lo split) ----------
// BM=64 x BN=64 x BK=32; 16 col-tiles (x, always active) x 8 row-tiles (y)
// x 32 z -> ~1024 active blocks = 4/CU. 4 waves, quadrant 32x32, 2x2 frags.
// A rows come from COMPACTED Ehc/Elc (contiguous; no idx gather).
__global__ __launch_bounds__(256)
void k_proj(const unsigned short* __restrict__ Ehc, const unsigned short* __restrict__ Elc,
            const unsigned short* __restrict__ Wqh, const unsigned short* __restrict__ Wql,
            const unsigned short* __restrict__ Wkh, const unsigned short* __restrict__ Wkl,
            const float* __restrict__ bq, const float* __restrict__ bk,
            const int* __restrict__ n0, const int* __restrict__ n1,
            unsigned short* __restrict__ Ph, unsigned short* __restrict__ Pl){
  int z = blockIdx.z;
  int b = z >> 1, which = z & 1;
  int cnt = which ? n1[b] : n0[b];
  int rbase = blockIdx.y << 6;          // early-exit dim on y
  if (cnt == 0 || rbase >= cnt) return;
  const unsigned short* __restrict__ Wh = which ? Wkh : Wqh;
  const unsigned short* __restrict__ Wl = which ? Wkl : Wql;
  const float* __restrict__ bias = which ? bk : bq;
  int dstOff = which ? n0[b] : 0;
  int cbase = blockIdx.x << 6;          // always-active dim on x (16 tiles)

  __shared__ __align__(16) char Ah[64 * LROW], Al[64 * LROW];
  __shared__ __align__(16) char Bh[64 * LROW], Bl[64 * LROW];

  int t = threadIdx.x;
  int w = t >> 6, lane = t & 63;
  int wm = w >> 1, wn = w & 1;
  int fr = lane & 15, kg = lane >> 4;

  // staging: 64 rows x 4 16B-chunks, 1 chunk/thread for each of A(h,l), B(h,l)
  int srow = t >> 2, schk = t & 3;
  int ar = min(rbase + srow, cnt - 1);
  size_t aoff = ((size_t)b * NSEQ + dstOff + ar) * NDIM + schk * 8;
  const unsigned short* aSh = Ehc + aoff;
  const unsigned short* aSl = Elc + aoff;
  const unsigned short* bSh = Wh + (size_t)(cbase + srow) * NDIM + schk * 8;
  const unsigned short* bSl = Wl + (size_t)(cbase + srow) * NDIM + schk * 8;
  char* aDh = Ah + srow * LROW + schk * 16;
  char* aDl = Al + srow * LROW + schk * 16;
  char* bDh = Bh + srow * LROW + schk * 16;
  char* bDl = Bl + srow * LROW + schk * 16;

  f32x4 acc[2][2];
  #pragma unroll
  for (int i = 0; i < 2; ++i)
    #pragma unroll
    for (int j = 0; j < 2; ++j) acc[i][j] = (f32x4){0.f, 0.f, 0.f, 0.f};

  uint4 v0 = *(const uint4*)(aSh);
  uint4 v1 = *(const uint4*)(aSl);
  uint4 v2 = *(const uint4*)(bSh);
  uint4 v3 = *(const uint4*)(bSl);

  for (int k0 = 0; k0 < NDIM; k0 += 32){
    __syncthreads();
    *(uint4*)aDh = v0; *(uint4*)aDl = v1;
    *(uint4*)bDh = v2; *(uint4*)bDl = v3;
    __syncthreads();

    int kn = k0 + 32;
    if (kn < NDIM){
      v0 = *(const uint4*)(aSh + kn);
      v1 = *(const uint4*)(aSl + kn);
      v2 = *(const uint4*)(bSh + kn);
      v3 = *(const uint4*)(bSl + kn);
    }

    bf16x8 ah[2], al_[2], bh[2], bl_[2];
    #pragma unroll
    for (int fm = 0; fm < 2; ++fm){
      int r = wm * 32 + fm * 16 + fr;
      ah[fm]  = *(const bf16x8*)(Ah + r * LROW + kg * 16);
      al_[fm] = *(const bf16x8*)(Al + r * LROW + kg * 16);
    }
    #pragma unroll
    for (int fn = 0; fn < 2; ++fn){
      int r = wn * 32 + fn * 16 + fr;
      bh[fn]  = *(const bf16x8*)(Bh + r * LROW + kg * 16);
      bl_[fn] = *(const bf16x8*)(Bl + r * LROW + kg * 16);
    }
    #pragma unroll
    for (int fm = 0; fm < 2; ++fm)
      #pragma unroll
      for (int fn = 0; fn < 2; ++fn){
        acc[fm][fn] = __builtin_amdgcn_mfma_f32_16x16x32_bf16(ah[fm], bh[fn], acc[fm][fn], 0, 0, 0);
        acc[fm][fn] = __builtin_amdgcn_mfma_f32_16x16x32_bf16(ah[fm], bl_[fn], acc[fm][fn], 0, 0, 0);
        acc[fm][fn] = __builtin_amdgcn_mfma_f32_16x16x32_bf16(al_[fm], bh[fn], acc[fm][fn], 0, 0, 0);
      }
  }

  // C/D layout (m89-verified): col = lane&15, row = (lane>>4)*4 + reg
  #pragma unroll
  for (int fm = 0; fm < 2; ++fm)
    #pragma unroll
    for (int fn = 0; fn < 2; ++fn)
      #pragma unroll
      for (int reg = 0; reg < 4; ++reg){
        int rloc = wm * 32 + fm * 16 + (kg << 2) + reg;
        if (rbase + rloc < cnt){
          int gc = cbase + wn * 32 + fn * 16 + fr;
          float v = acc[fm][fn][reg] + bias[gc];
          unsigned short h, l; split1(v, h, l);
          size_t o = ((size_t)b * NSEQ + dstOff + rbase + rloc) * NDIM + gc;
          Ph[o] = h; Pl[o] = l;
        }
      }
}

// ---------------- pair phase: MFMA logits + |cos| + tile softmax partials --
// GRID: x = batch (always active), y = i-tile, z = j-tile. Compacted inputs:
// Q/K from Ph/Pl, E/F from Ehc/Elc; rnormc direct (no idx gather).
__global__ __launch_bounds__(256)
void k_pair(const unsigned short* __restrict__ Ph, const unsigned short* __restrict__ Pl,
            const unsigned short* __restrict__ Ehc, const unsigned short* __restrict__ Elc,
            const int* __restrict__ n0a, const int* __restrict__ n1a,
            const float* __restrict__ rnormc, float* __restrict__ partials){
  int b = blockIdx.x;
  int nn0 = n0a[b], nn1 = n1a[b];
  int ibase = blockIdx.y << 5, jbase = blockIdx.z << 5;
  if (nn0 == 0 || nn1 == 0 || ibase >= nn0 || jbase >= nn1) return;

  __shared__ __align__(16) char stage[8 * 32 * LROW];  // Qh Ql Kh Kl Eh El Fh Fl
  __shared__ __align__(16) float Lout[1024];
  __shared__ __align__(16) float Sout[1024];
  __shared__ float red[12];

  int t = threadIdx.x;
  int w = t >> 6, lane = t & 63;
  int ih = w >> 1, jh = w & 1;
  int fr = lane & 15, kg = lane >> 4;

  int tile = t >> 5, srow = t & 31;
  const unsigned short* src;
  {
    int ci = min(ibase + srow, nn0 - 1);
    int cj = min(jbase + srow, nn1 - 1);
    const unsigned short* hb; size_t r;
    switch (tile){
      case 0: hb = Ph;  r = (size_t)b * NSEQ + ci; break;
      case 1: hb = Pl;  r = (size_t)b * NSEQ + ci; break;
      case 2: hb = Ph;  r = (size_t)b * NSEQ + nn0 + cj; break;
      case 3: hb = Pl;  r = (size_t)b * NSEQ + nn0 + cj; break;
      case 4: hb = Ehc; r = (size_t)b * NSEQ + ci; break;
      case 5: hb = Elc; r = (size_t)b * NSEQ + ci; break;
      case 6: hb = Ehc; r = (size_t)b * NSEQ + nn0 + cj; break;
      default: hb = Elc; r = (size_t)b * NSEQ + nn0 + cj; break;
    }
    src = hb + r * NDIM;
  }
  char* dst = stage + tile * (32 * LROW) + srow * LROW;
  char* Qh_ = stage;
  char* Ql_ = stage + 1 * (32 * LROW);
  char* Kh_ = stage + 2 * (32 * LROW);
  char* Kl_ = stage + 3 * (32 * LROW);
  char* Eh_ = stage + 4 * (32 * LROW);
  char* El_ = stage + 5 * (32 * LROW);
  char* Fh_ = stage + 6 * (32 * LROW);
  char* Fl_ = stage + 7 * (32 * LROW);

  f32x4 accL = (f32x4){0.f, 0.f, 0.f, 0.f};
  f32x4 accS = (f32x4){0.f, 0.f, 0.f, 0.f};
  int qrow = ih * 16 + fr, krow = jh * 16 + fr;

  uint4 v0 = *(const uint4*)(src);
  uint4 v1 = *(const uint4*)(src + 8);
  uint4 v2 = *(const uint4*)(src + 16);
  uint4 v3 = *(const uint4*)(src + 24);

  for (int k0 = 0; k0 < NDIM; k0 += 32){
    __syncthreads();
    *(uint4*)(dst)      = v0;
    *(uint4*)(dst + 16) = v1;
    *(uint4*)(dst + 32) = v2;
    *(uint4*)(dst + 48) = v3;
    __syncthreads();

    int kn = k0 + 32;
    if (kn < NDIM){
      v0 = *(const uint4*)(src + kn);
      v1 = *(const uint4*)(src + kn + 8);
      v2 = *(const uint4*)(src + kn + 16);
      v3 = *(const uint4*)(src + kn + 24);
    }

    bf16x8 qh = *(const bf16x8*)(Qh_ + qrow * LROW + kg * 16);
    bf16x8 ql = *(const bf16x8*)(Ql_ + qrow * LROW + kg * 16);
    bf16x8 kh = *(const bf16x8*)(Kh_ + krow * LROW + kg * 16);
    bf16x8 kl = *(const bf16x8*)(Kl_ + krow * LROW + kg * 16);
    bf16x8 eh = *(const bf16x8*)(Eh_ + qrow * LROW + kg * 16);
    bf16x8 el = *(const bf16x8*)(El_ + qrow * LROW + kg * 16);
    bf16x8 fh = *(const bf16x8*)(Fh_ + krow * LROW + kg * 16);
    bf16x8 fl = *(const bf16x8*)(Fl_ + krow * LROW + kg * 16);

    accL = __builtin_amdgcn_mfma_f32_16x16x32_bf16(qh, kh, accL, 0, 0, 0);
    accL = __builtin_amdgcn_mfma_f32_16x16x32_bf16(qh, kl, accL, 0, 0, 0);
    accL = __builtin_amdgcn_mfma_f32_16x16x32_bf16(ql, kh, accL, 0, 0, 0);
    accS = __builtin_amdgcn_mfma_f32_16x16x32_bf16(eh, fh, accS, 0, 0, 0);
    accS = __builtin_amdgcn_mfma_f32_16x16x32_bf16(eh, fl, accS, 0, 0, 0);
    accS = __builtin_amdgcn_mfma_f32_16x16x32_bf16(el, fh, accS, 0, 0, 0);
  }

  __syncthreads();
  #pragma unroll
  for (int reg = 0; reg < 4; ++reg){
    int li = ih * 16 + (kg << 2) + reg, lj = jh * 16 + fr;
    Lout[li * 32 + lj] = accL[reg];
    Sout[li * 32 + lj] = accS[reg];
  }
  __syncthreads();

  float m = NEGBIG, dsum = 0.f, nsum = 0.f;
  #pragma unroll
  for (int u = 0; u < 4; ++u){
    int l = t + (u << 8);
    int i = l >> 5, j = l & 31;
    if ((ibase + i < nn0) && (jbase + j < nn1)){
      float L = Lout[l];
      float S = Sout[l];
      float rnI = rnormc[b * NSEQ + ibase + i];
      float rnJ = rnormc[b * NSEQ + nn0 + jbase + j];
      float mm = fmaxf(m, L);
      float wold = expf(m - mm);
      float e = expf(L - mm);
      dsum = dsum * wold + e;
      nsum = nsum * wold + e * fabsf(S) * rnI * rnJ;
      m = mm;
    }
  }
  #pragma unroll
  for (int off = 1; off < 64; off <<= 1){
    float m2 = __shfl_xor(m, off, 64);
    float d2 = __shfl_xor(dsum, off, 64);
    float s2 = __shfl_xor(nsum, off, 64);
    float mm = fmaxf(m, m2);
    float w1 = expf(m - mm), w2 = expf(m2 - mm);
    dsum = dsum * w1 + d2 * w2;
    nsum = nsum * w1 + s2 * w2;
    m = mm;
  }
  if (lane == 0){ red[w * 3 + 0] = m; red[w * 3 + 1] = dsum; red[w * 3 + 2] = nsum; }
  __syncthreads();
  if (t == 0){
    float M = NEGBIG, D = 0.f, N = 0.f;
    #pragma unroll
    for (int ww = 0; ww < 4; ++ww){
      float m2 = red[ww * 3 + 0], d2 = red[ww * 3 + 1], n2 = red[ww * 3 + 2];
      float mm = fmaxf(M, m2);
      float w1 = expf(M - mm), w2 = expf(m2 - mm);
      D = D * w1 + d2 * w2;
      N = N * w1 + n2 * w2;
      M = mm;
    }
    float* pp = partials + ((size_t)b * 256 + (blockIdx.y << 4) + blockIdx.z) * 3;
    pp[0] = M; pp[1] = D; pp[2] = N;
  }
}

// ---------------- finalize: merge tile partials per batch ----------------
__global__ __launch_bounds__(64)
void k_final(const float* __restrict__ partials, const int* __restrict__ n0a,
             const int* __restrict__ n1a, float* __restrict__ out){
  int b = blockIdx.x, lane = threadIdx.x;
  int nn0 = n0a[b], nn1 = n1a[b];
  float m = NEGBIG, d = 0.f, n = 0.f;
  if (nn0 > 0 && nn1 > 0){
    int nti = (nn0 + 31) >> 5, ntj = (nn1 + 31) >> 5;
    int cnt = nti * ntj;
    for (int s = lane; s < cnt; s += 64){
      int it = s / ntj, jt = s - it * ntj;
      const float* pp = partials + ((size_t)b * 256 + (it << 4) + jt) * 3;
      float m2 = pp[0], d2 = pp[1], n2 = pp[2];
      float mm = fmaxf(m, m2);
      float w1 = expf(m - mm), w2 = expf(m2 - mm);
      d = d * w1 + d2 * w2;
      n = n * w1 + n2 * w2;
      m = mm;
    }
  }
  #pragma unroll
  for (int off = 1; off < 64; off <<= 1){
    float m2 = __shfl_xor(m, off, 64);
    float d2 = __shfl_xor(d, off, 64);
    float n2 = __shfl_xor(n, off, 64);
    float mm = fmaxf(m, m2);
    float w1 = expf(m - mm), w2 = expf(m2 - mm);
    d = d * w1 + d2 * w2;
    n = n * w1 + n2 * w2;
    m = mm;
  }
  if (lane == 0) out[b] = (d > 0.f) ? (n / d) : 0.f;
}

extern "C" void kernel_launch(void* const* d_in, const int* in_sizes, int n_in,
                              void* d_out, int out_size, void* d_ws, size_t ws_size,
                              hipStream_t stream) {
  const float* emb = (const float*)d_in[0];
  const float* Wq  = (const float*)d_in[1];
  const float* bq  = (const float*)d_in[2];
  const float* Wk  = (const float*)d_in[3];
  const float* bk  = (const float*)d_in[4];
  const int*   am  = (const int*)d_in[5];
  const int*   tt  = (const int*)d_in[6];
  float* out = (float*)d_out;

  // workspace layout (~72.2 MB)
  char* ws = (char*)d_ws;
  unsigned short* Ehc = (unsigned short*)(ws);                        // 16 MB
  unsigned short* Elc = (unsigned short*)(ws + (1u << 24));           // 16 MB
  unsigned short* Ph  = (unsigned short*)(ws + 2u * (1u << 24));      // 16 MB
  unsigned short* Pl  = (unsigned short*)(ws + 3u * (1u << 24));      // 16 MB
  unsigned short* Wqh = (unsigned short*)(ws + 4u * (1u << 24));      // 2 MB
  unsigned short* Wql = (unsigned short*)(ws + 4u * (1u << 24) + 1u * (1u << 21));
  unsigned short* Wkh = (unsigned short*)(ws + 4u * (1u << 24) + 2u * (1u << 21));
  unsigned short* Wkl = (unsigned short*)(ws + 4u * (1u << 24) + 3u * (1u << 21));
  char* misc = ws + 4u * (1u << 24) + 4u * (1u << 21);
  int*   idx0  = (int*)misc;
  int*   idx1  = idx0 + NBATCH * NSEQ;
  int*   n0    = idx1 + NBATCH * NSEQ;
  int*   n1    = n0 + NBATCH;
  float* rnormc = (float*)(n1 + NBATCH);
  float* partials = rnormc + NBATCH * NSEQ;

  k_compact<<<dim3(NBATCH), dim3(NSEQ), 0, stream>>>(am, tt, idx0, idx1, n0, n1);
  k_conv2<<<dim3(NBATCH, 128), dim3(256), 0, stream>>>(emb, idx0, idx1, n0, n1,
                                                       Ehc, Elc, rnormc);
  k_conv<<<dim3(512), dim3(256), 0, stream>>>(Wq, Wqh, Wql, NDIM * NDIM / 8);
  k_conv<<<dim3(512), dim3(256), 0, stream>>>(Wk, Wkh, Wkl, NDIM * NDIM / 8);
  // x = always-active col-tiles (16); y = early-exit row-tiles
  k_proj<<<dim3(16, 8, NBATCH * 2), dim3(256), 0, stream>>>(Ehc, Elc, Wqh, Wql, Wkh, Wkl,
                                                            bq, bk, n0, n1, Ph, Pl);
  k_pair<<<dim3(NBATCH, 16, 16), dim3(256), 0, stream>>>(Ph, Pl, Ehc, Elc,
                                                         n0, n1, rnormc, partials);
  k_final<<<dim3(NBATCH), dim3(64), 0, stream>>>(partials, n0, n1, out);
}

// Round 14
// 208.899 us; speedup vs baseline: 24.2261x; 1.1127x over previous
//
#include <hip/hip_runtime.h>
#include <math.h>

#define NBATCH 16
#define NSEQ   512
#define NDIM   1024
#define NEGBIG (-1e30f)

typedef __attribute__((ext_vector_type(8))) short bf16x8;
typedef __attribute__((ext_vector_type(8))) unsigned short u16x8;
typedef __attribute__((ext_vector_type(4))) float f32x4;

// LDS row stride for 32-bf16 (64B) tile rows: 80B (odd multiple of 16B).
#define LROW 80

// f32 -> bf16 hi (truncate) + bf16 lo (exact residual, truncated).
__device__ __forceinline__ void split1(float f, unsigned short& h, unsigned short& l){
  unsigned u = __float_as_uint(f);
  h = (unsigned short)(u >> 16);
  float fl = f - __uint_as_float(u & 0xffff0000u);
  l = (unsigned short)(__float_as_uint(fl) >> 16);
}

// ---------------- mask compaction ----------------
__global__ __launch_bounds__(512)
void k_compact(const int* __restrict__ am, const int* __restrict__ tt,
               int* __restrict__ idx0, int* __restrict__ idx1,
               int* __restrict__ n0, int* __restrict__ n1){
  int b = blockIdx.x, t = threadIdx.x;
  int a = am[b * NSEQ + t];
  int y = tt[b * NSEQ + t];
  bool p0 = (a == 1) && (y == 0);
  bool p1 = (a == 1) && (y == 1);
  __shared__ int wc0[8], wc1[8], wo0[8], wo1[8];
  int wave = t >> 6, lane = t & 63;
  unsigned long long m0 = __ballot(p0);
  unsigned long long m1 = __ballot(p1);
  unsigned long long below = (1ULL << lane) - 1ULL;
  int r0 = __popcll(m0 & below);
  int r1 = __popcll(m1 & below);
  if (lane == 0){ wc0[wave] = __popcll(m0); wc1[wave] = __popcll(m1); }
  __syncthreads();
  if (t == 0){
    int s0 = 0, s1 = 0;
    for (int w = 0; w < 8; ++w){ wo0[w] = s0; s0 += wc0[w]; wo1[w] = s1; s1 += wc1[w]; }
    n0[b] = s0; n1[b] = s1;
  }
  __syncthreads();
  if (p0) idx0[b * NSEQ + wo0[wave] + r0] = t;
  if (p1) idx1[b * NSEQ + wo1[wave] + r1] = t;
}

// ---------------- fused: gather compacted rows, rnorm + bf16 hi/lo split ---
__global__ __launch_bounds__(256)
void k_conv2(const float* __restrict__ emb, const int* __restrict__ idx0,
             const int* __restrict__ idx1, const int* __restrict__ n0,
             const int* __restrict__ n1, unsigned short* __restrict__ Ehc,
             unsigned short* __restrict__ Elc, float* __restrict__ rnormc){
  int b = blockIdx.x;
  int wave = threadIdx.x >> 6, lane = threadIdx.x & 63;
  int pos = blockIdx.y * 4 + wave;
  int nn0 = n0[b], nn1 = n1[b];
  if (pos >= nn0 + nn1) return;
  int srcRow = (pos < nn0) ? idx0[b * NSEQ + pos] : idx1[b * NSEQ + pos - nn0];
  const float4* src = (const float4*)(emb + ((size_t)b * NSEQ + srcRow) * NDIM);
  float4 v[4];
  float ss = 0.f;
  #pragma unroll
  for (int i = 0; i < 4; ++i){
    v[i] = src[i * 64 + lane];
    ss += v[i].x*v[i].x + v[i].y*v[i].y + v[i].z*v[i].z + v[i].w*v[i].w;
  }
  #pragma unroll
  for (int off = 32; off > 0; off >>= 1) ss += __shfl_down(ss, off, 64);
  if (lane == 0) rnormc[b * NSEQ + pos] = 1.f / fmaxf(sqrtf(ss), 1e-12f);
  size_t dst = ((size_t)b * NSEQ + pos) * NDIM;
  #pragma unroll
  for (int i = 0; i < 4; ++i){
    ushort4 h, l;
    split1(v[i].x, h.x, l.x); split1(v[i].y, h.y, l.y);
    split1(v[i].z, h.z, l.z); split1(v[i].w, h.w, l.w);
    *(ushort4*)(Ehc + dst + (size_t)(i * 64 + lane) * 4) = h;
    *(ushort4*)(Elc + dst + (size_t)(i * 64 + lane) * 4) = l;
  }
}

// ---------------- f32 -> bf16 hi/lo pre-conversion (weights) ----------------
__global__ __launch_bounds__(256)
void k_conv(const float* __restrict__ src, unsigned short* __restrict__ hi,
            unsigned short* __restrict__ lo, int n8){
  int t = blockIdx.x * 256 + threadIdx.x;
  if (t >= n8) return;
  const float4* s = (const float4*)(src + (size_t)t * 8);
  float4 a = s[0], b = s[1];
  float v[8] = {a.x, a.y, a.z, a.w, b.x, b.y, b.z, b.w};
  u16x8 h, l;
  #pragma unroll
  for (int i = 0; i < 8; ++i){
    unsigned short hh, ll; split1(v[i], hh, ll); h[i] = hh; l[i] = ll;
  }
  *(u16x8*)(hi + (size_t)t * 8) = h;
  *(u16x8*)(lo + (size_t)t * 8) = l;
}

// ---------------- MFMA projection GEMM (bf16 3-pass hi/lo split) ----------
// BM=64 x BN=64 x BK=32; x = 16 col-tiles (always active), y = row-tiles.
__global__ __launch_bounds__(256)
void k_proj(const unsigned short* __restrict__ Ehc, const unsigned short* __restrict__ Elc,
            const unsigned short* __restrict__ Wqh, const unsigned short* __restrict__ Wql,
            const unsigned short* __restrict__ Wkh, const unsigned short* __restrict__ Wkl,
            const float* __restrict__ bq, const float* __restrict__ bk,
            const int* __restrict__ n0, const int* __restrict__ n1,
            unsigned short* __restrict__ Ph, unsigned short* __restrict__ Pl){
  int z = blockIdx.z;
  int b = z >> 1, which = z & 1;
  int cnt = which ? n1[b] : n0[b];
  int rbase = blockIdx.y << 6;
  if (cnt == 0 || rbase >= cnt) return;
  const unsigned short* __restrict__ Wh = which ? Wkh : Wqh;
  const unsigned short* __restrict__ Wl = which ? Wkl : Wql;
  const float* __restrict__ bias = which ? bk : bq;
  int dstOff = which ? n0[b] : 0;
  int cbase = blockIdx.x << 6;

  __shared__ __align__(16) char Ah[64 * LROW], Al[64 * LROW];
  __shared__ __align__(16) char Bh[64 * LROW], Bl[64 * LROW];

  int t = threadIdx.x;
  int w = t >> 6, lane = t & 63;
  int wm = w >> 1, wn = w & 1;
  int fr = lane & 15, kg = lane >> 4;

  int srow = t >> 2, schk = t & 3;
  int ar = min(rbase + srow, cnt - 1);
  size_t aoff = ((size_t)b * NSEQ + dstOff + ar) * NDIM + schk * 8;
  const unsigned short* aSh = Ehc + aoff;
  const unsigned short* aSl = Elc + aoff;
  const unsigned short* bSh = Wh + (size_t)(cbase + srow) * NDIM + schk * 8;
  const unsigned short* bSl = Wl + (size_t)(cbase + srow) * NDIM + schk * 8;
  char* aDh = Ah + srow * LROW + schk * 16;
  char* aDl = Al + srow * LROW + schk * 16;
  char* bDh = Bh + srow * LROW + schk * 16;
  char* bDl = Bl + srow * LROW + schk * 16;

  f32x4 acc[2][2];
  #pragma unroll
  for (int i = 0; i < 2; ++i)
    #pragma unroll
    for (int j = 0; j < 2; ++j) acc[i][j] = (f32x4){0.f, 0.f, 0.f, 0.f};

  uint4 v0 = *(const uint4*)(aSh);
  uint4 v1 = *(const uint4*)(aSl);
  uint4 v2 = *(const uint4*)(bSh);
  uint4 v3 = *(const uint4*)(bSl);

  for (int k0 = 0; k0 < NDIM; k0 += 32){
    __syncthreads();
    *(uint4*)aDh = v0; *(uint4*)aDl = v1;
    *(uint4*)bDh = v2; *(uint4*)bDl = v3;
    __syncthreads();

    int kn = k0 + 32;
    if (kn < NDIM){
      v0 = *(const uint4*)(aSh + kn);
      v1 = *(const uint4*)(aSl + kn);
      v2 = *(const uint4*)(bSh + kn);
      v3 = *(const uint4*)(bSl + kn);
    }

    bf16x8 ah[2], al_[2], bh[2], bl_[2];
    #pragma unroll
    for (int fm = 0; fm < 2; ++fm){
      int r = wm * 32 + fm * 16 + fr;
      ah[fm]  = *(const bf16x8*)(Ah + r * LROW + kg * 16);
      al_[fm] = *(const bf16x8*)(Al + r * LROW + kg * 16);
    }
    #pragma unroll
    for (int fn = 0; fn < 2; ++fn){
      int r = wn * 32 + fn * 16 + fr;
      bh[fn]  = *(const bf16x8*)(Bh + r * LROW + kg * 16);
      bl_[fn] = *(const bf16x8*)(Bl + r * LROW + kg * 16);
    }
    #pragma unroll
    for (int fm = 0; fm < 2; ++fm)
      #pragma unroll
      for (int fn = 0; fn < 2; ++fn){
        acc[fm][fn] = __builtin_amdgcn_mfma_f32_16x16x32_bf16(ah[fm], bh[fn], acc[fm][fn], 0, 0, 0);
        acc[fm][fn] = __builtin_amdgcn_mfma_f32_16x16x32_bf16(ah[fm], bl_[fn], acc[fm][fn], 0, 0, 0);
        acc[fm][fn] = __builtin_amdgcn_mfma_f32_16x16x32_bf16(al_[fm], bh[fn], acc[fm][fn], 0, 0, 0);
      }
  }

  // C/D layout (m89-verified): col = lane&15, row = (lane>>4)*4 + reg
  #pragma unroll
  for (int fm = 0; fm < 2; ++fm)
    #pragma unroll
    for (int fn = 0; fn < 2; ++fn)
      #pragma unroll
      for (int reg = 0; reg < 4; ++reg){
        int rloc = wm * 32 + fm * 16 + (kg << 2) + reg;
        if (rbase + rloc < cnt){
          int gc = cbase + wn * 32 + fn * 16 + fr;
          float v = acc[fm][fn][reg] + bias[gc];
          unsigned short h, l; split1(v, h, l);
          size_t o = ((size_t)b * NSEQ + dstOff + rbase + rloc) * NDIM + gc;
          Ph[o] = h; Pl[o] = l;
        }
      }
}

// ---------------- pair phase: 8 waves, K split in halves ----------------
// 32x32 tile; waves 0-3 (quadrants) process K in [0,512), waves 4-7 the
// same quadrants for K in [512,1024). Each half stages its own LDS slices;
// halves combined in LDS before the block softmax partial phase.
__global__ __launch_bounds__(512)
void k_pair(const unsigned short* __restrict__ Ph, const unsigned short* __restrict__ Pl,
            const unsigned short* __restrict__ Ehc, const unsigned short* __restrict__ Elc,
            const int* __restrict__ n0a, const int* __restrict__ n1a,
            const float* __restrict__ rnormc, float* __restrict__ partials){
  int b = blockIdx.x;
  int nn0 = n0a[b], nn1 = n1a[b];
  int ibase = blockIdx.y << 5, jbase = blockIdx.z << 5;
  if (nn0 == 0 || nn1 == 0 || ibase >= nn0 || jbase >= nn1) return;

  __shared__ __align__(16) char stage[2 * 8 * 32 * LROW]; // [half][tensor][32*LROW]
  __shared__ __align__(16) float Lout[1024];
  __shared__ __align__(16) float Sout[1024];
  __shared__ float red[24];

  int t = threadIdx.x;
  int w = t >> 6, lane = t & 63;
  int half = w >> 2, quad = w & 3;          // K-half, output quadrant
  int ih = quad >> 1, jh = quad & 1;
  int fr = lane & 15, kg = lane >> 4;

  // staging: threads 0-255 stage half 0's 8 tiles, 256-511 half 1's.
  int t2 = t & 255;
  int tile = t2 >> 5, srow = t2 & 31;       // tensor tile 0..7, row 0..31
  const unsigned short* src;
  {
    int ci = min(ibase + srow, nn0 - 1);
    int cj = min(jbase + srow, nn1 - 1);
    const unsigned short* hb; size_t r;
    switch (tile){
      case 0: hb = Ph;  r = (size_t)b * NSEQ + ci; break;
      case 1: hb = Pl;  r = (size_t)b * NSEQ + ci; break;
      case 2: hb = Ph;  r = (size_t)b * NSEQ + nn0 + cj; break;
      case 3: hb = Pl;  r = (size_t)b * NSEQ + nn0 + cj; break;
      case 4: hb = Ehc; r = (size_t)b * NSEQ + ci; break;
      case 5: hb = Elc; r = (size_t)b * NSEQ + ci; break;
      case 6: hb = Ehc; r = (size_t)b * NSEQ + nn0 + cj; break;
      default: hb = Elc; r = (size_t)b * NSEQ + nn0 + cj; break;
    }
    src = hb + r * NDIM + half * 512;       // this half's K slice
  }
  char* dst = stage + (half * 8 + tile) * (32 * LROW) + srow * LROW;
  char* base = stage + half * 8 * (32 * LROW);
  char* Qh_ = base;
  char* Ql_ = base + 1 * (32 * LROW);
  char* Kh_ = base + 2 * (32 * LROW);
  char* Kl_ = base + 3 * (32 * LROW);
  char* Eh_ = base + 4 * (32 * LROW);
  char* El_ = base + 5 * (32 * LROW);
  char* Fh_ = base + 6 * (32 * LROW);
  char* Fl_ = base + 7 * (32 * LROW);

  f32x4 accL = (f32x4){0.f, 0.f, 0.f, 0.f};
  f32x4 accS = (f32x4){0.f, 0.f, 0.f, 0.f};
  int qrow = ih * 16 + fr, krow = jh * 16 + fr;

  uint4 v0 = *(const uint4*)(src);
  uint4 v1 = *(const uint4*)(src + 8);
  uint4 v2 = *(const uint4*)(src + 16);
  uint4 v3 = *(const uint4*)(src + 24);

  for (int k0 = 0; k0 < 512; k0 += 32){
    __syncthreads();
    *(uint4*)(dst)      = v0;
    *(uint4*)(dst + 16) = v1;
    *(uint4*)(dst + 32) = v2;
    *(uint4*)(dst + 48) = v3;
    __syncthreads();

    int kn = k0 + 32;
    if (kn < 512){
      v0 = *(const uint4*)(src + kn);
      v1 = *(const uint4*)(src + kn + 8);
      v2 = *(const uint4*)(src + kn + 16);
      v3 = *(const uint4*)(src + kn + 24);
    }

    bf16x8 qh = *(const bf16x8*)(Qh_ + qrow * LROW + kg * 16);
    bf16x8 ql = *(const bf16x8*)(Ql_ + qrow * LROW + kg * 16);
    bf16x8 kh = *(const bf16x8*)(Kh_ + krow * LROW + kg * 16);
    bf16x8 kl = *(const bf16x8*)(Kl_ + krow * LROW + kg * 16);
    bf16x8 eh = *(const bf16x8*)(Eh_ + qrow * LROW + kg * 16);
    bf16x8 el = *(const bf16x8*)(El_ + qrow * LROW + kg * 16);
    bf16x8 fh = *(const bf16x8*)(Fh_ + krow * LROW + kg * 16);
    bf16x8 fl = *(const bf16x8*)(Fl_ + krow * LROW + kg * 16);

    accL = __builtin_amdgcn_mfma_f32_16x16x32_bf16(qh, kh, accL, 0, 0, 0);
    accL = __builtin_amdgcn_mfma_f32_16x16x32_bf16(qh, kl, accL, 0, 0, 0);
    accL = __builtin_amdgcn_mfma_f32_16x16x32_bf16(ql, kh, accL, 0, 0, 0);
    accS = __builtin_amdgcn_mfma_f32_16x16x32_bf16(eh, fh, accS, 0, 0, 0);
    accS = __builtin_amdgcn_mfma_f32_16x16x32_bf16(eh, fl, accS, 0, 0, 0);
    accS = __builtin_amdgcn_mfma_f32_16x16x32_bf16(el, fh, accS, 0, 0, 0);
  }

  // combine halves: half 0 writes, half 1 adds
  __syncthreads();
  if (half == 0){
    #pragma unroll
    for (int reg = 0; reg < 4; ++reg){
      int li = ih * 16 + (kg << 2) + reg, lj = jh * 16 + fr;
      Lout[li * 32 + lj] = accL[reg];
      Sout[li * 32 + lj] = accS[reg];
    }
  }
  __syncthreads();
  if (half == 1){
    #pragma unroll
    for (int reg = 0; reg < 4; ++reg){
      int li = ih * 16 + (kg << 2) + reg, lj = jh * 16 + fr;
      Lout[li * 32 + lj] += accL[reg];
      Sout[li * 32 + lj] += accS[reg];
    }
  }
  __syncthreads();

  // block-wide flattened softmax partials (512 threads, 2 elems each)
  float m = NEGBIG, dsum = 0.f, nsum = 0.f;
  #pragma unroll
  for (int u = 0; u < 2; ++u){
    int l = t + (u << 9);
    int i = l >> 5, j = l & 31;
    if ((ibase + i < nn0) && (jbase + j < nn1)){
      float L = Lout[l];
      float S = Sout[l];
      float rnI = rnormc[b * NSEQ + ibase + i];
      float rnJ = rnormc[b * NSEQ + nn0 + jbase + j];
      float mm = fmaxf(m, L);
      float wold = expf(m - mm);
      float e = expf(L - mm);
      dsum = dsum * wold + e;
      nsum = nsum * wold + e * fabsf(S) * rnI * rnJ;
      m = mm;
    }
  }
  #pragma unroll
  for (int off = 1; off < 64; off <<= 1){
    float m2 = __shfl_xor(m, off, 64);
    float d2 = __shfl_xor(dsum, off, 64);
    float s2 = __shfl_xor(nsum, off, 64);
    float mm = fmaxf(m, m2);
    float w1 = expf(m - mm), w2 = expf(m2 - mm);
    dsum = dsum * w1 + d2 * w2;
    nsum = nsum * w1 + s2 * w2;
    m = mm;
  }
  if (lane == 0){ red[w * 3 + 0] = m; red[w * 3 + 1] = dsum; red[w * 3 + 2] = nsum; }
  __syncthreads();
  if (t == 0){
    float M = NEGBIG, D = 0.f, N = 0.f;
    #pragma unroll
    for (int ww = 0; ww < 8; ++ww){
      float m2 = red[ww * 3 + 0], d2 = red[ww * 3 + 1], n2 = red[ww * 3 + 2];
      float mm = fmaxf(M, m2);
      float w1 = expf(M - mm), w2 = expf(m2 - mm);
      D = D * w1 + d2 * w2;
      N = N * w1 + n2 * w2;
      M = mm;
    }
    float* pp = partials + ((size_t)b * 256 + (blockIdx.y << 4) + blockIdx.z) * 3;
    pp[0] = M; pp[1] = D; pp[2] = N;
  }
}

// ---------------- finalize: merge tile partials per batch ----------------
__global__ __launch_bounds__(64)
void k_final(const float* __restrict__ partials, const int* __restrict__ n0a,
             const int* __restrict__ n1a, float* __restrict__ out){
  int b = blockIdx.x, lane = threadIdx.x;
  int nn0 = n0a[b], nn1 = n1a[b];
  float m = NEGBIG, d = 0.f, n = 0.f;
  if (nn0 > 0 && nn1 > 0){
    int nti = (nn0 + 31) >> 5, ntj = (nn1 + 31) >> 5;
    int cnt = nti * ntj;
    for (int s = lane; s < cnt; s += 64){
      int it = s / ntj, jt = s - it * ntj;
      const float* pp = partials + ((size_t)b * 256 + (it << 4) + jt) * 3;
      float m2 = pp[0], d2 = pp[1], n2 = pp[2];
      float mm = fmaxf(m, m2);
      float w1 = expf(m - mm), w2 = expf(m2 - mm);
      d = d * w1 + d2 * w2;
      n = n * w1 + n2 * w2;
      m = mm;
    }
  }
  #pragma unroll
  for (int off = 1; off < 64; off <<= 1){
    float m2 = __shfl_xor(m, off, 64);
    float d2 = __shfl_xor(d, off, 64);
    float n2 = __shfl_xor(n, off, 64);
    float mm = fmaxf(m, m2);
    float w1 = expf(m - mm), w2 = expf(m2 - mm);
    d = d * w1 + d2 * w2;
    n = n * w1 + n2 * w2;
    m = mm;
  }
  if (lane == 0) out[b] = (d > 0.f) ? (n / d) : 0.f;
}

extern "C" void kernel_launch(void* const* d_in, const int* in_sizes, int n_in,
                              void* d_out, int out_size, void* d_ws, size_t ws_size,
                              hipStream_t stream) {
  const float* emb = (const float*)d_in[0];
  const float* Wq  = (const float*)d_in[1];
  const float* bq  = (const float*)d_in[2];
  const float* Wk  = (const float*)d_in[3];
  const float* bk  = (const float*)d_in[4];
  const int*   am  = (const int*)d_in[5];
  const int*   tt  = (const int*)d_in[6];
  float* out = (float*)d_out;

  // workspace layout (~72.2 MB)
  char* ws = (char*)d_ws;
  unsigned short* Ehc = (unsigned short*)(ws);                        // 16 MB
  unsigned short* Elc = (unsigned short*)(ws + (1u << 24));           // 16 MB
  unsigned short* Ph  = (unsigned short*)(ws + 2u * (1u << 24));      // 16 MB
  unsigned short* Pl  = (unsigned short*)(ws + 3u * (1u << 24));      // 16 MB
  unsigned short* Wqh = (unsigned short*)(ws + 4u * (1u << 24));      // 2 MB
  unsigned short* Wql = (unsigned short*)(ws + 4u * (1u << 24) + 1u * (1u << 21));
  unsigned short* Wkh = (unsigned short*)(ws + 4u * (1u << 24) + 2u * (1u << 21));
  unsigned short* Wkl = (unsigned short*)(ws + 4u * (1u << 24) + 3u * (1u << 21));
  char* misc = ws + 4u * (1u << 24) + 4u * (1u << 21);
  int*   idx0  = (int*)misc;
  int*   idx1  = idx0 + NBATCH * NSEQ;
  int*   n0    = idx1 + NBATCH * NSEQ;
  int*   n1    = n0 + NBATCH;
  float* rnormc = (float*)(n1 + NBATCH);
  float* partials = rnormc + NBATCH * NSEQ;

  k_compact<<<dim3(NBATCH), dim3(NSEQ), 0, stream>>>(am, tt, idx0, idx1, n0, n1);
  k_conv2<<<dim3(NBATCH, 128), dim3(256), 0, stream>>>(emb, idx0, idx1, n0, n1,
                                                       Ehc, Elc, rnormc);
  k_conv<<<dim3(512), dim3(256), 0, stream>>>(Wq, Wqh, Wql, NDIM * NDIM / 8);
  k_conv<<<dim3(512), dim3(256), 0, stream>>>(Wk, Wkh, Wkl, NDIM * NDIM / 8);
  k_proj<<<dim3(16, 8, NBATCH * 2), dim3(256), 0, stream>>>(Ehc, Elc, Wqh, Wql, Wkh, Wkl,
                                                            bq, bk, n0, n1, Ph, Pl);
  k_pair<<<dim3(NBATCH, 16, 16), dim3(512), 0, stream>>>(Ph, Pl, Ehc, Elc,
                                                         n0, n1, rnormc, partials);
  k_final<<<dim3(NBATCH), dim3(64), 0, stream>>>(partials, n0, n1, out);
}